// Round 9
// baseline (486.839 us; speedup 1.0000x reference)
//
#include <hip/hip_runtime.h>
#include <cstdint>
#include <cstddef>

// ---------------- Mamba2 fwd: bf16-MFMA + LDS-staged full-line stores ----------------
// B=2 L=2048 Dmodel=1024 Dssm=2048 H=32 P=64 N=128 chunk=256
#define B_SZ   2
#define LQ     2048
#define DMODEL 1024
#define DSSM   2048
#define NH     32
#define HD     64
#define DST    128
#define CONVD  2304
#define DPROJ  4384
#define NC     8
#define CHK    256
#define MROWS  (B_SZ*LQ)   // 4096

#define SWZ256(r) (((r) & 15) << 4)
#define SWZ64(r)  (((((r) & 7) ^ (((r) >> 3) & 7))) << 4)

__device__ __forceinline__ float silu_f(float x) { return x / (1.f + expf(-x)); }
__device__ __forceinline__ float softplus_f(float x) {
  return fmaxf(x, 0.f) + log1pf(expf(-fabsf(x)));
}
__device__ __forceinline__ ushort f2bf(float f) {  // RNE fp32->bf16
  uint32_t u = __float_as_uint(f);
  uint32_t r = (u + 0x7FFFu + ((u >> 16) & 1u)) >> 16;
  return (ushort)r;
}
__device__ __forceinline__ float bf2f(ushort u) {
  return __uint_as_float(((uint32_t)u) << 16);
}

typedef __bf16 bf16x8 __attribute__((ext_vector_type(8)));
typedef float f32x4 __attribute__((ext_vector_type(4)));

// ============================================================
// cast fp32 -> bf16 (as ushort), 4 elems/thread
// ============================================================
__global__ __launch_bounds__(256) void cast_f32_bf16_kernel(
    const float* __restrict__ in, ushort* __restrict__ out, int n) {
  const int i = (blockIdx.x * 256 + threadIdx.x) * 4;
  if (i >= n) return;
  float4 v = *(const float4*)&in[i];
  ushort4 o;
  o.x = f2bf(v.x); o.y = f2bf(v.y); o.z = f2bf(v.z); o.w = f2bf(v.w);
  *(ushort4*)&out[i] = o;
}

// ============================================================
// bf16 MFMA GEMM (NT): C[m][n] = sum_k A[m][k]*B[n][k].
// Operand-swapped mfma; epilogue STAGES the C tile in LDS and copies
// out with >=256B contiguous per row per store instruction (HBM write
// granule — partial writes were 7.8x amplified, R7 counters).
// ============================================================
template<bool BF16OUT>
__global__ __launch_bounds__(256, 4) void gemm_nt_bf16(
    const ushort* __restrict__ A, const ushort* __restrict__ Bm,
    void* __restrict__ Cout, int M, int N, int K) {
  __shared__ ushort sh[128 * 128];   // 32 KB: As | Bs during K-loop, C-stage after
  ushort* As = sh;
  ushort* Bs = sh + 128 * 64;
  const int t = threadIdx.x;
  const int lane = t & 63;
  const int wid = t >> 6;
  const int wm = (wid >> 1) * 64;
  const int wn = (wid & 1) * 64;
  const int lr = lane & 15;
  const int lkb = (lane >> 4) * 8;   // k-elem offset for frag loads
  const int lk4 = (lane >> 4) * 4;   // n sub-offset in D
  // XCD swizzle (bijective: nwg % 8 == 0)
  const int gx = gridDim.x;
  int lin = blockIdx.y * gx + blockIdx.x;
  const int q8 = (gx * gridDim.y) >> 3;
  lin = (lin & 7) * q8 + (lin >> 3);
  const int m0 = (lin / gx) * 128;
  const int n0 = (lin % gx) * 128;
  const int srow = t >> 3;
  const int sce = (t & 7) * 8;

  f32x4 acc[4][4];
#pragma unroll
  for (int i = 0; i < 4; ++i)
#pragma unroll
    for (int j = 0; j < 4; ++j) acc[i][j] = (f32x4){0.f, 0.f, 0.f, 0.f};

  const int NT = K >> 6;
  for (int kt = 0; kt < NT; ++kt) {
    const int k0 = kt << 6;
    uint4 ar[4], br[4];
#pragma unroll
    for (int s2 = 0; s2 < 4; ++s2) {
      const int row = srow + s2 * 32;
      ar[s2] = *(const uint4*)&A[(size_t)(m0 + row) * K + k0 + sce];
      const int gn = n0 + row;
      br[s2] = (gn < N) ? *(const uint4*)&Bm[(size_t)gn * K + k0 + sce]
                        : make_uint4(0u, 0u, 0u, 0u);
    }
    __syncthreads();
#pragma unroll
    for (int s2 = 0; s2 < 4; ++s2) {
      const int row = srow + s2 * 32;
      const int e = (row * 64 + sce) ^ ((row & 7) << 3);
      *(uint4*)&As[e] = ar[s2];
      *(uint4*)&Bs[e] = br[s2];
    }
    __syncthreads();
#pragma unroll
    for (int ks = 0; ks < 2; ++ks) {
      bf16x8 af[4], bfr[4];
#pragma unroll
      for (int i = 0; i < 4; ++i) {
        const int ra = wm + i * 16 + lr;
        const int ea = (ra * 64 + ks * 32 + lkb) ^ ((ra & 7) << 3);
        af[i] = *(const bf16x8*)&As[ea];
        const int rb = wn + i * 16 + lr;
        const int eb = (rb * 64 + ks * 32 + lkb) ^ ((rb & 7) << 3);
        bfr[i] = *(const bf16x8*)&Bs[eb];
      }
      // swapped operands: lane's 4 D-elems = 4 consecutive n at fixed m
#pragma unroll
      for (int i = 0; i < 4; ++i)
#pragma unroll
        for (int j = 0; j < 4; ++j)
          acc[i][j] = __builtin_amdgcn_mfma_f32_16x16x32_bf16(bfr[j], af[i], acc[i][j], 0, 0, 0);
    }
  }
  // ---------- LDS-staged epilogue ----------
  __syncthreads();  // all frag reads of As/Bs done
  if constexpr (BF16OUT) {
    // stage full 128x128 bf16 tile (32 KB)
#pragma unroll
    for (int i = 0; i < 4; ++i) {
      const int ml = wm + i * 16 + lr;
#pragma unroll
      for (int j = 0; j < 4; ++j) {
        ushort4 o;
        o.x = f2bf(acc[i][j][0]); o.y = f2bf(acc[i][j][1]);
        o.z = f2bf(acc[i][j][2]); o.w = f2bf(acc[i][j][3]);
        *(ushort4*)&sh[ml * 128 + wn + j * 16 + lk4] = o;
      }
    }
    __syncthreads();
    ushort* Cg = (ushort*)Cout;
#pragma unroll
    for (int it = 0; it < 8; ++it) {
      const int idx = it * 256 + t;          // 0..2047
      const int r = idx >> 4;                // 0..127
      const int cc = (idx & 15) * 8;         // col (ushort)
      const int gn = n0 + cc;
      if (gn < N)
        *(uint4*)&Cg[(size_t)(m0 + r) * N + gn] = *(const uint4*)&sh[r * 128 + cc];
    }
  } else {
    // fp32: two half-tile passes (64 rows x 128 cols = 32 KB each)
    float* Cf = (float*)sh;
    float* Cg = (float*)Cout;
#pragma unroll
    for (int p = 0; p < 2; ++p) {
      __syncthreads();
#pragma unroll
      for (int i2 = 0; i2 < 2; ++i2) {
        const int i = p * 2 + i2;
        const int cr = (wid >> 1) * 32 + i2 * 16 + lr;   // compressed row 0..63
#pragma unroll
        for (int j = 0; j < 4; ++j)
          *(float4*)&Cf[cr * 128 + wn + j * 16 + lk4] =
              make_float4(acc[i][j][0], acc[i][j][1], acc[i][j][2], acc[i][j][3]);
      }
      __syncthreads();
#pragma unroll
      for (int it = 0; it < 8; ++it) {
        const int idx = it * 256 + t;        // 0..2047
        const int cr = idx >> 5;             // 0..63
        const int cc = (idx & 31) * 4;
        const int gm = m0 + (cr >> 5) * 64 + p * 32 + (cr & 31);
        const int gn = n0 + cc;
        if (gn < N)
          *(float4*)&Cg[(size_t)gm * N + gn] = *(const float4*)&Cf[cr * 128 + cc];
      }
    }
  }
}

// ============================================================
// fp32 dt: recompute dt columns exactly (exp-amplified path)
// ============================================================
__global__ __launch_bounds__(256) void dt_kernel(
    const float* __restrict__ u, const float* __restrict__ w,
    const float* __restrict__ dt_bias, const float* __restrict__ A_log,
    float* __restrict__ dt_bhl, float* __restrict__ dA_bhl) {
  const int m = blockIdx.x;
  const int b = m >> 11;
  const int l = m & 2047;
  __shared__ float us[DMODEL];
  const int t = threadIdx.x;
  *(float4*)&us[t * 4] = *(const float4*)&u[(size_t)m * DMODEL + t * 4];
  __syncthreads();
  const int h = t >> 3;
  const int seg = t & 7;
  const float* wr = &w[(size_t)(DSSM + CONVD + h) * DMODEL + seg * 128];
  const float* uu = &us[seg * 128];
  float s = 0.f;
#pragma unroll
  for (int k = 0; k < 128; k += 4) {
    float4 wv = *(const float4*)&wr[k];
    s = fmaf(wv.x, uu[k + 0], s);
    s = fmaf(wv.y, uu[k + 1], s);
    s = fmaf(wv.z, uu[k + 2], s);
    s = fmaf(wv.w, uu[k + 3], s);
  }
  s += __shfl_down(s, 4, 8);
  s += __shfl_down(s, 2, 8);
  s += __shfl_down(s, 1, 8);
  if (seg == 0) {
    const float dtv = softplus_f(s + dt_bias[h]);
    const size_t o = ((size_t)b * NH + h) * LQ + l;
    dt_bhl[o] = dtv;
    dA_bhl[o] = -expf(A_log[h]) * dtv;
  }
}

// ============================================================
// Depthwise causal conv(K=4)+bias+SiLU over xBC. bf16 in/out, fp32 math.
// ============================================================
__global__ __launch_bounds__(256) void conv_kernel(
    const ushort* __restrict__ zx, const float* __restrict__ conv_w,
    const float* __restrict__ conv_b, ushort* __restrict__ xconv) {
  const int ROWS = 16;
  const int nrb = LQ / ROWS;
  const int blk = blockIdx.x;
  const int b = blk / nrb;
  const int r0 = (blk % nrb) * ROWS;
  const int t = threadIdx.x;

  float w0[9], w1[9], w2[9], w3[9], bsv[9], h0[9], h1[9], h2[9];
#pragma unroll
  for (int j = 0; j < 9; ++j) {
    const int cch = t + 256 * j;
    w0[j] = conv_w[cch * 4 + 0]; w1[j] = conv_w[cch * 4 + 1];
    w2[j] = conv_w[cch * 4 + 2]; w3[j] = conv_w[cch * 4 + 3];
    bsv[j] = conv_b[cch];
    h0[j] = (r0 - 3 >= 0) ? bf2f(zx[(size_t)(b * LQ + r0 - 3) * DPROJ + DSSM + cch]) : 0.f;
    h1[j] = (r0 - 2 >= 0) ? bf2f(zx[(size_t)(b * LQ + r0 - 2) * DPROJ + DSSM + cch]) : 0.f;
    h2[j] = (r0 - 1 >= 0) ? bf2f(zx[(size_t)(b * LQ + r0 - 1) * DPROJ + DSSM + cch]) : 0.f;
  }
  for (int r = 0; r < ROWS; ++r) {
    const size_t ibase = (size_t)(b * LQ + r0 + r) * DPROJ + DSSM;
    const size_t obase = (size_t)(b * LQ + r0 + r) * CONVD;
#pragma unroll
    for (int j = 0; j < 9; ++j) {
      const int cch = t + 256 * j;
      const float cur = bf2f(zx[ibase + cch]);
      float a = bsv[j] + w0[j] * h0[j] + w1[j] * h1[j] + w2[j] * h2[j] + w3[j] * cur;
      xconv[obase + cch] = f2bf(silu_f(a));
      h0[j] = h1[j]; h1[j] = h2[j]; h2[j] = cur;
    }
  }
}

// ============================================================
// Stage a [64 rows][128 cols] bf16 tile -> LDS, 256B pitch, SWZ256.
// ============================================================
__device__ __forceinline__ void stage_tile_128w(
    ushort* sh, const ushort* __restrict__ src, int src_stride, int t) {
  const int r = t >> 2;
  const int cb = (t & 3) * 32;
  const ushort* s = &src[(size_t)r * src_stride + cb];
  uint4 q0 = *(const uint4*)&s[0];
  uint4 q1 = *(const uint4*)&s[8];
  uint4 q2 = *(const uint4*)&s[16];
  uint4 q3 = *(const uint4*)&s[24];
  char* shb = (char*)sh + r * 256;
  const int c0 = cb * 2;
  *(uint4*)(shb + ((c0 +  0) ^ SWZ256(r))) = q0;
  *(uint4*)(shb + ((c0 + 16) ^ SWZ256(r))) = q1;
  *(uint4*)(shb + ((c0 + 32) ^ SWZ256(r))) = q2;
  *(uint4*)(shb + ((c0 + 48) ^ SWZ256(r))) = q3;
}

// ============================================================
// Per (b,c,h): cumsum(dA) scan + intra-chunk states via MFMA.
// Epilogue staged through LDS -> 4KB contiguous bursts.
// ============================================================
__global__ __launch_bounds__(256) void chunk_states_mfma(
    const ushort* __restrict__ xconv, const float* __restrict__ dt_bhl,
    const float* __restrict__ dA_bhl, float* __restrict__ dA_cs_g,
    float* __restrict__ Tg, ushort* __restrict__ states_bf) {
  const int blk = blockIdx.x;
  const int h = blk & (NH - 1);
  const int c = (blk / NH) & (NC - 1);
  const int b = blk / (NH * NC);
  const int t = threadIdx.x;
  const int lane = t & 63;
  const int wid = t >> 6;
  const int lr = lane & 15;
  const int lk = lane >> 4;
  __shared__ float cs[CHK];
  __shared__ ushort Xt2[64 * 64];   // [p][l] 128B pitch, SWZ64
  __shared__ ushort Bt2[128 * 64];  // [n][l] 128B pitch, SWZ64; reused as C-stage
  const size_t bh = (size_t)b * NH + h;
  const int rowbase = b * LQ + c * CHK;

  cs[t] = dA_bhl[bh * LQ + c * CHK + t];
  __syncthreads();
#pragma unroll
  for (int off = 1; off < CHK; off <<= 1) {
    const float add = (t >= off) ? cs[t - off] : 0.f;
    __syncthreads();
    cs[t] += add;
    __syncthreads();
  }
  const float total = cs[CHK - 1];
  dA_cs_g[(bh * NC + c) * CHK + t] = cs[t];
  if (t == 0) Tg[bh * NC + c] = total;

  f32x4 acc[4][2];
#pragma unroll
  for (int i = 0; i < 4; ++i)
#pragma unroll
    for (int j = 0; j < 2; ++j) acc[i][j] = (f32x4){0.f, 0.f, 0.f, 0.f};

  for (int lt = 0; lt < 4; ++lt) {
    const int l0 = lt * 64;
    __syncthreads();
    {  // stage Xt2: rows l -> [p][l], factor dt*exp(total-cs)
      const int sr = t >> 2;
      const int pb = (t & 3) * 16;
      const float f = dt_bhl[bh * LQ + c * CHK + l0 + sr] * expf(total - cs[l0 + sr]);
      const ushort* xs = &xconv[(size_t)(rowbase + l0 + sr) * CONVD + h * HD + pb];
      ushort xv[16];
      *(uint4*)&xv[0] = *(const uint4*)&xs[0];
      *(uint4*)&xv[8] = *(const uint4*)&xs[8];
      char* Xb = (char*)Xt2;
#pragma unroll
      for (int e = 0; e < 16; ++e) {
        const int p = pb + e;
        *(ushort*)(Xb + (p * 128 + ((sr * 2) ^ SWZ64(p)))) = f2bf(bf2f(xv[e]) * f);
      }
    }
    {  // stage Bt2: rows l -> [n][l]
      const int sr = t >> 2;
      const int nb = (t & 3) * 32;
      const ushort* bs = &xconv[(size_t)(rowbase + l0 + sr) * CONVD + DSSM + nb];
      ushort bv[32];
      *(uint4*)&bv[0]  = *(const uint4*)&bs[0];
      *(uint4*)&bv[8]  = *(const uint4*)&bs[8];
      *(uint4*)&bv[16] = *(const uint4*)&bs[16];
      *(uint4*)&bv[24] = *(const uint4*)&bs[24];
      char* Bb = (char*)Bt2;
#pragma unroll
      for (int e = 0; e < 32; ++e) {
        const int n = nb + e;
        *(ushort*)(Bb + (n * 128 + ((sr * 2) ^ SWZ64(n)))) = bv[e];
      }
    }
    __syncthreads();
#pragma unroll
    for (int ks = 0; ks < 2; ++ks) {
      const int kb = (ks * 32 + lk * 8) * 2;
      bf16x8 a4[4], b2[2];
#pragma unroll
      for (int i = 0; i < 4; ++i) {
        const int p = i * 16 + lr;
        a4[i] = *(const bf16x8*)((char*)Xt2 + (p * 128 + (kb ^ SWZ64(p))));
      }
#pragma unroll
      for (int j = 0; j < 2; ++j) {
        const int n = wid * 32 + j * 16 + lr;
        b2[j] = *(const bf16x8*)((char*)Bt2 + (n * 128 + (kb ^ SWZ64(n))));
      }
#pragma unroll
      for (int i = 0; i < 4; ++i)
#pragma unroll
        for (int j = 0; j < 2; ++j)
          acc[i][j] = __builtin_amdgcn_mfma_f32_16x16x32_bf16(a4[i], b2[j], acc[i][j], 0, 0, 0);
    }
  }
  // ---------- LDS-staged store: [p][n] linear (16 KB) ----------
  __syncthreads();
#pragma unroll
  for (int i = 0; i < 4; ++i)
#pragma unroll
    for (int j = 0; j < 2; ++j)
#pragma unroll
      for (int q = 0; q < 4; ++q)
        Bt2[(i * 16 + lk * 4 + q) * 128 + wid * 32 + j * 16 + lr] = f2bf(acc[i][j][q]);
  __syncthreads();
  const size_t sbase = ((size_t)((b * NC + c) * NH) + h) * (HD * DST);
#pragma unroll
  for (int it = 0; it < 4; ++it) {
    const int idx = it * 256 + t;  // 0..1023
    *(uint4*)&states_bf[sbase + (size_t)idx * 8] = *(const uint4*)&Bt2[idx * 8];
  }
}

// ============================================================
// Inter-chunk recurrence: reads states_bf, keeps P fp32, writes prev_bf.
// ============================================================
__global__ __launch_bounds__(256) void chunk_scan_kernel(
    const ushort* __restrict__ states_bf, ushort* __restrict__ prev_bf,
    const float* __restrict__ Tg) {
  const int blk = blockIdx.x;
  const int s = blk & 7;
  const int bh = blk >> 3;
  const int b = bh / NH;
  const int h = bh % NH;
  const int e = s * 1024 + threadIdx.x * 4;
  float4 P = make_float4(0.f, 0.f, 0.f, 0.f);
#pragma unroll
  for (int c = 0; c < NC; ++c) {
    const size_t idx = ((size_t)((b * NC + c) * NH) + h) * (HD * DST) + e;
    ushort4 s4 = *(const ushort4*)&states_bf[idx];
    ushort4 o;
    o.x = f2bf(P.x); o.y = f2bf(P.y); o.z = f2bf(P.z); o.w = f2bf(P.w);
    *(ushort4*)&prev_bf[idx] = o;
    const float ec = expf(Tg[(size_t)bh * NC + c]);
    P.x = fmaf(ec, P.x, bf2f(s4.x)); P.y = fmaf(ec, P.y, bf2f(s4.y));
    P.z = fmaf(ec, P.z, bf2f(s4.z)); P.w = fmaf(ec, P.w, bf2f(s4.w));
  }
}

// ============================================================
// Per (b,c,h): Y = (L ∘ C B^T) X + exp(cs)⊙(C prev^T) + D*x  via MFMA.
// y output in [H][M][64] layout -> per-lt tile is one contiguous 8 KB
// region; stored via LDS stage + 4 KB linear bursts.
// ============================================================
__global__ __launch_bounds__(256) void y_mfma_kernel(
    const ushort* __restrict__ xconv, const float* __restrict__ dt_bhl,
    const float* __restrict__ dA_cs_g, const ushort* __restrict__ prevb,
    const float* __restrict__ Dp, ushort* __restrict__ y2) {
  const int blk = blockIdx.x;
  const int h = blk & (NH - 1);
  const int c = (blk / NH) & (NC - 1);
  const int b = blk / (NH * NC);
  const int t = threadIdx.x;
  const int lane = t & 63;
  const int wid = t >> 6;
  const int wr = (wid >> 1) * 32;   // l-range base of this wave
  const int wc = (wid & 1) * 32;    // p/s-range base of this wave
  const int lr = lane & 15;
  const int lk = lane >> 4;
  __shared__ float cs[CHK];
  __shared__ ushort Ct[64 * 128];   // C tile, 256B pitch, SWZ256
  __shared__ ushort Bs[64 * 128];   // B tile, 256B pitch, SWZ256
  __shared__ ushort Gt[64 * 64];    // G tile (l x s) SWZ64; reused as Y-stage
  __shared__ ushort Xt[64 * 64];    // X^T tile (p x s), SWZ64
  const size_t bh = (size_t)b * NH + h;
  const size_t prevbase = ((size_t)((b * NC + c) * NH) + h) * (HD * DST);
  const int rowbase = b * LQ + c * CHK;
  cs[t] = dA_cs_g[(bh * NC + c) * CHK + t];
  const float Dh = Dp[h];
  __syncthreads();

  for (int lt = 0; lt < 4; ++lt) {
    const int l0 = lt * 64;
    __syncthreads();  // protect Ct/Gt/Xt from previous iteration readers
    stage_tile_128w(Ct, &xconv[(size_t)(rowbase + l0) * CONVD + DSSM + DST], CONVD, t);
    __syncthreads();
    bf16x8 af[2][4];
#pragma unroll
    for (int i = 0; i < 2; ++i)
#pragma unroll
      for (int ks = 0; ks < 4; ++ks) {
        const int row = wr + i * 16 + lr;
        af[i][ks] = *(const bf16x8*)((char*)Ct +
            (row * 256 + (((ks * 32 + lk * 8) * 2) ^ SWZ256(row))));
      }
    f32x4 acc[2][2];
#pragma unroll
    for (int i = 0; i < 2; ++i)
#pragma unroll
      for (int j = 0; j < 2; ++j) acc[i][j] = (f32x4){0.f, 0.f, 0.f, 0.f};
#pragma unroll
    for (int ks = 0; ks < 4; ++ks) {
      bf16x8 bp[2];
#pragma unroll
      for (int j = 0; j < 2; ++j) {
        const int p = wc + j * 16 + lr;
        bp[j] = *(const bf16x8*)&prevb[prevbase + (size_t)p * DST + ks * 32 + lk * 8];
      }
#pragma unroll
      for (int i = 0; i < 2; ++i)
#pragma unroll
        for (int j = 0; j < 2; ++j)
          acc[i][j] = __builtin_amdgcn_mfma_f32_16x16x32_bf16(af[i][ks], bp[j], acc[i][j], 0, 0, 0);
    }
#pragma unroll
    for (int i = 0; i < 2; ++i) {
#pragma unroll
      for (int q = 0; q < 4; ++q) {
        const float e = expf(cs[l0 + wr + i * 16 + lk * 4 + q]);
        acc[i][0][q] *= e;
        acc[i][1][q] *= e;
      }
    }

    for (int st = 0; st <= lt; ++st) {
      const int s0 = st * 64;
      __syncthreads();
      stage_tile_128w(Bs, &xconv[(size_t)(rowbase + s0) * CONVD + DSSM], CONVD, t);
      {  // stage Xt: rows s of x*dt -> [p][s]
        const int sr = t >> 2;
        const int pb = (t & 3) * 16;
        const float f = dt_bhl[bh * LQ + c * CHK + s0 + sr];
        const ushort* xs = &xconv[(size_t)(rowbase + s0 + sr) * CONVD + h * HD + pb];
        ushort xv[16];
        *(uint4*)&xv[0] = *(const uint4*)&xs[0];
        *(uint4*)&xv[8] = *(const uint4*)&xs[8];
        char* Xb = (char*)Xt;
#pragma unroll
        for (int e = 0; e < 16; ++e) {
          const int p = pb + e;
          *(ushort*)(Xb + (p * 128 + ((sr * 2) ^ SWZ64(p)))) = f2bf(bf2f(xv[e]) * f);
        }
      }
      __syncthreads();
      // G = C B^T
      f32x4 g2[2][2];
#pragma unroll
      for (int i = 0; i < 2; ++i)
#pragma unroll
        for (int j = 0; j < 2; ++j) g2[i][j] = (f32x4){0.f, 0.f, 0.f, 0.f};
#pragma unroll
      for (int ks = 0; ks < 4; ++ks) {
        bf16x8 bb[2];
#pragma unroll
        for (int j = 0; j < 2; ++j) {
          const int srow = wc + j * 16 + lr;
          bb[j] = *(const bf16x8*)((char*)Bs +
              (srow * 256 + (((ks * 32 + lk * 8) * 2) ^ SWZ256(srow))));
        }
#pragma unroll
        for (int i = 0; i < 2; ++i)
#pragma unroll
          for (int j = 0; j < 2; ++j)
            g2[i][j] = __builtin_amdgcn_mfma_f32_16x16x32_bf16(af[i][ks], bb[j], g2[i][j], 0, 0, 0);
      }
      // decay + causal mask, write G (bf16) to LDS
      {
        char* Gb = (char*)Gt;
#pragma unroll
        for (int i = 0; i < 2; ++i) {
#pragma unroll
          for (int q = 0; q < 4; ++q) {
            const int lloc = wr + i * 16 + lk * 4 + q;
            const int labs = l0 + lloc;
            const float cl = cs[labs];
#pragma unroll
            for (int j = 0; j < 2; ++j) {
              const int sloc = wc + j * 16 + lr;
              const int sabs = s0 + sloc;
              const float gv = (labs >= sabs) ? g2[i][j][q] * expf(cl - cs[sabs]) : 0.f;
              *(ushort*)(Gb + (lloc * 128 + ((sloc * 2) ^ SWZ64(lloc)))) = f2bf(gv);
            }
          }
        }
      }
      __syncthreads();
      // Y += G X
#pragma unroll
      for (int ks2 = 0; ks2 < 2; ++ks2) {
        const int kb = (ks2 * 32 + lk * 8) * 2;
        bf16x8 ga[2], xb[2];
#pragma unroll
        for (int i = 0; i < 2; ++i) {
          const int lloc = wr + i * 16 + lr;
          ga[i] = *(const bf16x8*)((char*)Gt + (lloc * 128 + (kb ^ SWZ64(lloc))));
        }
#pragma unroll
        for (int j = 0; j < 2; ++j) {
          const int p = wc + j * 16 + lr;
          xb[j] = *(const bf16x8*)((char*)Xt + (p * 128 + (kb ^ SWZ64(p))));
        }
#pragma unroll
        for (int i = 0; i < 2; ++i)
#pragma unroll
          for (int j = 0; j < 2; ++j)
            acc[i][j] = __builtin_amdgcn_mfma_f32_16x16x32_bf16(ga[i], xb[j], acc[i][j], 0, 0, 0);
      }
    }
    // ---------- epilogue: +D*x, stage 64x64 Y tile in Gt, linear copy ----------
    __syncthreads();  // all waves done reading Gt
#pragma unroll
    for (int i = 0; i < 2; ++i)
#pragma unroll
      for (int j = 0; j < 2; ++j)
#pragma unroll
        for (int q = 0; q < 4; ++q) {
          const int lloc = wr + i * 16 + lk * 4 + q;
          const int p = wc + j * 16 + lr;
          const float xv = bf2f(xconv[(size_t)(rowbase + l0 + lloc) * CONVD + h * HD + p]);
          Gt[lloc * 64 + p] = f2bf(acc[i][j][q] + Dh * xv);
        }
    __syncthreads();
    {
      const size_t ybase = ((size_t)h * MROWS + rowbase + l0) * HD;
#pragma unroll
      for (int it = 0; it < 2; ++it) {
        const int idx = it * 256 + t;  // 0..511
        *(uint4*)&y2[ybase + (size_t)idx * 8] = *(const uint4*)&Gt[idx * 8];
      }
    }
  }
}

// ============================================================
// yg = y*silu(z); rmsnorm; y read from [H][M][64] layout.
// ============================================================
__global__ __launch_bounds__(256) void gate_norm_kernel(
    const ushort* __restrict__ zx, const float* __restrict__ norm_w,
    const ushort* __restrict__ y2, ushort* __restrict__ ygbf) {
  const int m = blockIdx.x;
  const int t = threadIdx.x;
  __shared__ float red[4];
  float g[8];
  float ssum = 0.f;
#pragma unroll
  for (int j = 0; j < 2; ++j) {
    const int cb = t * 4 + j * 1024;
    const int hh = cb >> 6;
    const int pp = cb & 63;
    ushort4 yv = *(const ushort4*)&y2[((size_t)hh * MROWS + m) * HD + pp];
    ushort4 zv = *(const ushort4*)&zx[(size_t)m * DPROJ + cb];
    const float yy[4] = {bf2f(yv.x), bf2f(yv.y), bf2f(yv.z), bf2f(yv.w)};
    const float zz[4] = {bf2f(zv.x), bf2f(zv.y), bf2f(zv.z), bf2f(zv.w)};
#pragma unroll
    for (int q = 0; q < 4; ++q) {
      const float gv = yy[q] * silu_f(zz[q]);
      g[j * 4 + q] = gv;
      ssum = fmaf(gv, gv, ssum);
    }
  }
#pragma unroll
  for (int off = 32; off > 0; off >>= 1) ssum += __shfl_down(ssum, off, 64);
  if ((t & 63) == 0) red[t >> 6] = ssum;
  __syncthreads();
  const float tot = red[0] + red[1] + red[2] + red[3];
  const float sc = 1.0f / sqrtf(tot / (float)DSSM + 1e-5f);
#pragma unroll
  for (int j = 0; j < 2; ++j) {
    const int cb = t * 4 + j * 1024;
    float4 nw = *(const float4*)&norm_w[cb];
    ushort4 o;
    o.x = f2bf(g[j * 4 + 0] * sc * nw.x);
    o.y = f2bf(g[j * 4 + 1] * sc * nw.y);
    o.z = f2bf(g[j * 4 + 2] * sc * nw.z);
    o.w = f2bf(g[j * 4 + 3] * sc * nw.w);
    *(ushort4*)&ygbf[(size_t)m * DSSM + cb] = o;
  }
}

// ============================================================
extern "C" void kernel_launch(void* const* d_in, const int* in_sizes, int n_in,
                              void* d_out, int out_size, void* d_ws, size_t ws_size,
                              hipStream_t stream) {
  const float* u          = (const float*)d_in[0];
  const float* in_proj_w  = (const float*)d_in[1];
  const float* conv_w     = (const float*)d_in[2];
  const float* conv_b     = (const float*)d_in[3];
  const float* dt_bias    = (const float*)d_in[4];
  const float* A_log      = (const float*)d_in[5];
  const float* Dp         = (const float*)d_in[6];
  const float* norm_w     = (const float*)d_in[7];
  const float* out_proj_w = (const float*)d_in[8];
  float* out = (float*)d_out;

  float* ws = (float*)d_ws;
  float* zxR     = ws;
  float* xconvR  = zxR     + (size_t)MROWS * DPROJ;
  float* dt_bhl  = xconvR  + (size_t)MROWS * CONVD;
  float* dA_bhl  = dt_bhl  + (size_t)B_SZ * NH * LQ;
  float* dA_cs   = dA_bhl  + (size_t)B_SZ * NH * LQ;
  float* Tg      = dA_cs   + (size_t)B_SZ * NH * LQ;
  float* statesR = Tg      + (size_t)B_SZ * NH * NC;
  float* ybufR   = statesR + (size_t)B_SZ * NC * NH * HD * DST;

  // bf16 views (same regions, footprint unchanged):
  ushort* zx_bf    = (ushort*)zxR;                       // 4096 x 4384 bf16
  ushort* xconv_bf = (ushort*)xconvR;                    // 4096 x 2304 bf16
  ushort* ow_bf    = xconv_bf + (size_t)MROWS * CONVD;   // out_proj_w bf16 (disjoint half)
  ushort* states_bf = (ushort*)statesR;
  ushort* prev_bf   = states_bf + (size_t)B_SZ * NC * NH * HD * DST;
  ushort* u_bf  = (ushort*)ybufR;                        // dead after in-gemm
  ushort* w_bf  = u_bf + (size_t)MROWS * DMODEL;         // dead after in-gemm
  ushort* y2_bf = (ushort*)ybufR;                        // y_mfma output, [H][M][64]
  ushort* yg_bf = y2_bf + (size_t)MROWS * DSSM;          // gate_norm output [M][2048]

  const int n_u = MROWS * DMODEL;
  const int n_w = DPROJ * DMODEL;
  const int n_o = DMODEL * DSSM;

  // 1) casts for in_proj
  cast_f32_bf16_kernel<<<dim3(n_u / 1024), 256, 0, stream>>>(u, u_bf, n_u);
  cast_f32_bf16_kernel<<<dim3(n_w / 1024), 256, 0, stream>>>(in_proj_w, w_bf, n_w);
  // 2) zxbcdt = u @ in_proj_w^T  (bf16 out, LDS-staged stores)
  gemm_nt_bf16<true><<<dim3((DPROJ + 127) / 128, MROWS / 128), 256, 0, stream>>>(
      u_bf, w_bf, zx_bf, MROWS, DPROJ, DMODEL);
  // 3) fp32 dt / dA
  dt_kernel<<<dim3(MROWS), 256, 0, stream>>>(u, in_proj_w, dt_bias, A_log, dt_bhl, dA_bhl);
  // 4) causal dwconv + SiLU (bf16 in/out)
  conv_kernel<<<dim3(B_SZ * (LQ / 16)), 256, 0, stream>>>(zx_bf, conv_w, conv_b, xconv_bf);
  // 5) per-chunk cumsum + intra-chunk states (MFMA, LDS-staged stores)
  chunk_states_mfma<<<dim3(B_SZ * NC * NH), 256, 0, stream>>>(
      xconv_bf, dt_bhl, dA_bhl, dA_cs, Tg, states_bf);
  // 6) inter-chunk recurrence
  chunk_scan_kernel<<<dim3(B_SZ * NH * 8), 256, 0, stream>>>(states_bf, prev_bf, Tg);
  // 7) Y (MFMA, [H][M][64] layout, LDS-staged stores)
  y_mfma_kernel<<<dim3(B_SZ * NC * NH), 256, 0, stream>>>(
      xconv_bf, dt_bhl, dA_cs, prev_bf, Dp, y2_bf);
  // 8) cast out_proj_w
  cast_f32_bf16_kernel<<<dim3(n_o / 1024), 256, 0, stream>>>(out_proj_w, ow_bf, n_o);
  // 9) gate + RMSNorm -> bf16 [M][2048]
  gate_norm_kernel<<<dim3(MROWS), 256, 0, stream>>>(zx_bf, norm_w, y2_bf, yg_bf);
  // 10) out = yg @ out_proj_w^T (fp32 out, LDS-staged stores)
  gemm_nt_bf16<false><<<dim3(DMODEL / 128, MROWS / 128), 256, 0, stream>>>(
      yg_bf, ow_bf, out, MROWS, DMODEL, DSSM);
}

// Round 12
// 356.799 us; speedup vs baseline: 1.3645x; 1.3645x over previous
//
#include <hip/hip_runtime.h>
#include <cstdint>
#include <cstddef>

// ---------------- Mamba2 fwd: bf16-MFMA + global_load_lds GEMM pipeline ----------------
// B=2 L=2048 Dmodel=1024 Dssm=2048 H=32 P=64 N=128 chunk=256
#define B_SZ   2
#define LQ     2048
#define DMODEL 1024
#define DSSM   2048
#define NH     32
#define HD     64
#define DST    128
#define CONVD  2304
#define DPROJ  4384
#define NC     8
#define CHK    256
#define MROWS  (B_SZ*LQ)   // 4096

#define SWZ256(r) (((r) & 15) << 4)
#define SWZ64(r)  (((((r) & 7) ^ (((r) >> 3) & 7))) << 4)

__device__ __forceinline__ float silu_f(float x) { return x / (1.f + expf(-x)); }
__device__ __forceinline__ float softplus_f(float x) {
  return fmaxf(x, 0.f) + log1pf(expf(-fabsf(x)));
}
__device__ __forceinline__ ushort f2bf(float f) {  // RNE fp32->bf16
  uint32_t u = __float_as_uint(f);
  uint32_t r = (u + 0x7FFFu + ((u >> 16) & 1u)) >> 16;
  return (ushort)r;
}
__device__ __forceinline__ float bf2f(ushort u) {
  return __uint_as_float(((uint32_t)u) << 16);
}
// async global->LDS DMA, 16B per lane; LDS dest = wave-uniform base + lane*16
__device__ __forceinline__ void gload_lds16(const ushort* g, ushort* l) {
  __builtin_amdgcn_global_load_lds(
      (const __attribute__((address_space(1))) void*)g,
      (__attribute__((address_space(3))) void*)l, 16, 0, 0);
}

typedef __bf16 bf16x8 __attribute__((ext_vector_type(8)));
typedef float f32x4 __attribute__((ext_vector_type(4)));

// ============================================================
// cast fp32 -> bf16 (as ushort), 4 elems/thread
// ============================================================
__global__ __launch_bounds__(256) void cast_f32_bf16_kernel(
    const float* __restrict__ in, ushort* __restrict__ out, int n) {
  const int i = (blockIdx.x * 256 + threadIdx.x) * 4;
  if (i >= n) return;
  float4 v = *(const float4*)&in[i];
  ushort4 o;
  o.x = f2bf(v.x); o.y = f2bf(v.y); o.z = f2bf(v.z); o.w = f2bf(v.w);
  *(ushort4*)&out[i] = o;
}

// ============================================================
// bf16 MFMA GEMM (NT): C[m][n] = sum_k A[m][k]*B[n][k].
// Staging via global_load_lds (16B/lane DMA), linear LDS dest +
// PRE-SWIZZLED global source column (same XOR involution as frag read).
// K-loop: barrier / issue 8 DMA / barrier(+vmcnt drain) / 32 MFMA.
// Epilogue: LDS-staged full-line stores (R9).
// ============================================================
template<bool BF16OUT>
__global__ __launch_bounds__(256, 4) void gemm_nt_bf16(
    const ushort* __restrict__ A, const ushort* __restrict__ Bm,
    void* __restrict__ Cout, int M, int N, int K) {
  __shared__ ushort sh[128 * 128];   // 32 KB: As | Bs during K-loop, C-stage after
  ushort* As = sh;
  ushort* Bs = sh + 128 * 64;
  const int t = threadIdx.x;
  const int lane = t & 63;
  const int wid = t >> 6;
  const int wm = (wid >> 1) * 64;
  const int wn = (wid & 1) * 64;
  const int lr = lane & 15;
  const int lkb = (lane >> 4) * 8;   // k-elem offset for frag loads
  const int lk4 = (lane >> 4) * 4;   // n sub-offset in D
  // XCD swizzle (bijective: nwg % 8 == 0)
  const int gx = gridDim.x;
  int lin = blockIdx.y * gx + blockIdx.x;
  const int q8 = (gx * gridDim.y) >> 3;
  lin = (lin & 7) * q8 + (lin >> 3);
  const int m0 = (lin / gx) * 128;
  const int n0 = (lin % gx) * 128;

  // staging geometry: wave w covers rows {s2*32 + w*8 + ric}, ric = lane>>3,
  // 16B (8 ushorts) per lane at column granule colq = (lane&7)*8.
  // Pre-swizzle source col by (row&7)<<3 == ric<<3 (rows are 8-aligned per wave).
  const int ric = lane >> 3;
  const int colsw = ((lane & 7) * 8) ^ (ric << 3);
  const size_t aoff0 = (size_t)(m0 + wid * 8 + ric) * K + colsw;
  size_t boff[4];
#pragma unroll
  for (int s2 = 0; s2 < 4; ++s2) {
    int gn = n0 + s2 * 32 + wid * 8 + ric;
    if (gn > N - 1) gn = N - 1;    // clamp tail rows (results masked at store)
    boff[s2] = (size_t)gn * K + colsw;
  }
  ushort* AsW = As + wid * 8 * 64;   // wave-uniform LDS base (s2=0)
  ushort* BsW = Bs + wid * 8 * 64;

  f32x4 acc[4][4];
#pragma unroll
  for (int i = 0; i < 4; ++i)
#pragma unroll
    for (int j = 0; j < 4; ++j) acc[i][j] = (f32x4){0.f, 0.f, 0.f, 0.f};

  const int NT = K >> 6;
  for (int kt = 0; kt < NT; ++kt) {
    const int k0 = kt << 6;
    __syncthreads();   // previous compute finished reading LDS
#pragma unroll
    for (int s2 = 0; s2 < 4; ++s2) {
      gload_lds16(&A[aoff0 + (size_t)s2 * 32 * K + k0], AsW + s2 * 32 * 64);
      gload_lds16(&Bm[boff[s2] + k0], BsW + s2 * 32 * 64);
    }
    __syncthreads();   // compiler drains vmcnt before barrier -> LDS ready
#pragma unroll
    for (int ks = 0; ks < 2; ++ks) {
      bf16x8 af[4], bfr[4];
#pragma unroll
      for (int i = 0; i < 4; ++i) {
        const int ra = wm + i * 16 + lr;
        const int ea = (ra * 64 + ks * 32 + lkb) ^ ((ra & 7) << 3);
        af[i] = *(const bf16x8*)&As[ea];
        const int rb = wn + i * 16 + lr;
        const int eb = (rb * 64 + ks * 32 + lkb) ^ ((rb & 7) << 3);
        bfr[i] = *(const bf16x8*)&Bs[eb];
      }
      // swapped operands: lane's 4 D-elems = 4 consecutive n at fixed m
#pragma unroll
      for (int i = 0; i < 4; ++i)
#pragma unroll
        for (int j = 0; j < 4; ++j)
          acc[i][j] = __builtin_amdgcn_mfma_f32_16x16x32_bf16(bfr[j], af[i], acc[i][j], 0, 0, 0);
    }
  }
  // ---------- LDS-staged epilogue ----------
  __syncthreads();  // all frag reads of As/Bs done
  if constexpr (BF16OUT) {
    // stage full 128x128 bf16 tile (32 KB)
#pragma unroll
    for (int i = 0; i < 4; ++i) {
      const int ml = wm + i * 16 + lr;
#pragma unroll
      for (int j = 0; j < 4; ++j) {
        ushort4 o;
        o.x = f2bf(acc[i][j][0]); o.y = f2bf(acc[i][j][1]);
        o.z = f2bf(acc[i][j][2]); o.w = f2bf(acc[i][j][3]);
        *(ushort4*)&sh[ml * 128 + wn + j * 16 + lk4] = o;
      }
    }
    __syncthreads();
    ushort* Cg = (ushort*)Cout;
#pragma unroll
    for (int it = 0; it < 8; ++it) {
      const int idx = it * 256 + t;          // 0..2047
      const int r = idx >> 4;                // 0..127
      const int cc = (idx & 15) * 8;         // col (ushort)
      const int gn = n0 + cc;
      if (gn < N)
        *(uint4*)&Cg[(size_t)(m0 + r) * N + gn] = *(const uint4*)&sh[r * 128 + cc];
    }
  } else {
    // fp32: two half-tile passes (64 rows x 128 cols = 32 KB each)
    float* Cf = (float*)sh;
    float* Cg = (float*)Cout;
#pragma unroll
    for (int p = 0; p < 2; ++p) {
      __syncthreads();
#pragma unroll
      for (int i2 = 0; i2 < 2; ++i2) {
        const int i = p * 2 + i2;
        const int cr = (wid >> 1) * 32 + i2 * 16 + lr;   // compressed row 0..63
#pragma unroll
        for (int j = 0; j < 4; ++j)
          *(float4*)&Cf[cr * 128 + wn + j * 16 + lk4] =
              make_float4(acc[i][j][0], acc[i][j][1], acc[i][j][2], acc[i][j][3]);
      }
      __syncthreads();
#pragma unroll
      for (int it = 0; it < 8; ++it) {
        const int idx = it * 256 + t;        // 0..2047
        const int cr = idx >> 5;             // 0..63
        const int cc = (idx & 31) * 4;
        const int gm = m0 + (cr >> 5) * 64 + p * 32 + (cr & 31);
        const int gn = n0 + cc;
        if (gn < N)
          *(float4*)&Cg[(size_t)gm * N + gn] = *(const float4*)&Cf[cr * 128 + cc];
      }
    }
  }
}

// ============================================================
// fp32 dt: recompute dt columns exactly (exp-amplified path)
// ============================================================
__global__ __launch_bounds__(256) void dt_kernel(
    const float* __restrict__ u, const float* __restrict__ w,
    const float* __restrict__ dt_bias, const float* __restrict__ A_log,
    float* __restrict__ dt_bhl, float* __restrict__ dA_bhl) {
  const int m = blockIdx.x;
  const int b = m >> 11;
  const int l = m & 2047;
  __shared__ float us[DMODEL];
  const int t = threadIdx.x;
  *(float4*)&us[t * 4] = *(const float4*)&u[(size_t)m * DMODEL + t * 4];
  __syncthreads();
  const int h = t >> 3;
  const int seg = t & 7;
  const float* wr = &w[(size_t)(DSSM + CONVD + h) * DMODEL + seg * 128];
  const float* uu = &us[seg * 128];
  float s = 0.f;
#pragma unroll
  for (int k = 0; k < 128; k += 4) {
    float4 wv = *(const float4*)&wr[k];
    s = fmaf(wv.x, uu[k + 0], s);
    s = fmaf(wv.y, uu[k + 1], s);
    s = fmaf(wv.z, uu[k + 2], s);
    s = fmaf(wv.w, uu[k + 3], s);
  }
  s += __shfl_down(s, 4, 8);
  s += __shfl_down(s, 2, 8);
  s += __shfl_down(s, 1, 8);
  if (seg == 0) {
    const float dtv = softplus_f(s + dt_bias[h]);
    const size_t o = ((size_t)b * NH + h) * LQ + l;
    dt_bhl[o] = dtv;
    dA_bhl[o] = -expf(A_log[h]) * dtv;
  }
}

// ============================================================
// Depthwise causal conv(K=4)+bias+SiLU over xBC. bf16 in/out, fp32 math.
// ============================================================
__global__ __launch_bounds__(256) void conv_kernel(
    const ushort* __restrict__ zx, const float* __restrict__ conv_w,
    const float* __restrict__ conv_b, ushort* __restrict__ xconv) {
  const int ROWS = 16;
  const int nrb = LQ / ROWS;
  const int blk = blockIdx.x;
  const int b = blk / nrb;
  const int r0 = (blk % nrb) * ROWS;
  const int t = threadIdx.x;

  float w0[9], w1[9], w2[9], w3[9], bsv[9], h0[9], h1[9], h2[9];
#pragma unroll
  for (int j = 0; j < 9; ++j) {
    const int cch = t + 256 * j;
    w0[j] = conv_w[cch * 4 + 0]; w1[j] = conv_w[cch * 4 + 1];
    w2[j] = conv_w[cch * 4 + 2]; w3[j] = conv_w[cch * 4 + 3];
    bsv[j] = conv_b[cch];
    h0[j] = (r0 - 3 >= 0) ? bf2f(zx[(size_t)(b * LQ + r0 - 3) * DPROJ + DSSM + cch]) : 0.f;
    h1[j] = (r0 - 2 >= 0) ? bf2f(zx[(size_t)(b * LQ + r0 - 2) * DPROJ + DSSM + cch]) : 0.f;
    h2[j] = (r0 - 1 >= 0) ? bf2f(zx[(size_t)(b * LQ + r0 - 1) * DPROJ + DSSM + cch]) : 0.f;
  }
  for (int r = 0; r < ROWS; ++r) {
    const size_t ibase = (size_t)(b * LQ + r0 + r) * DPROJ + DSSM;
    const size_t obase = (size_t)(b * LQ + r0 + r) * CONVD;
#pragma unroll
    for (int j = 0; j < 9; ++j) {
      const int cch = t + 256 * j;
      const float cur = bf2f(zx[ibase + cch]);
      float a = bsv[j] + w0[j] * h0[j] + w1[j] * h1[j] + w2[j] * h2[j] + w3[j] * cur;
      xconv[obase + cch] = f2bf(silu_f(a));
      h0[j] = h1[j]; h1[j] = h2[j]; h2[j] = cur;
    }
  }
}

// ============================================================
// Stage a [64 rows][128 cols] bf16 tile -> LDS, 256B pitch, SWZ256.
// ============================================================
__device__ __forceinline__ void stage_tile_128w(
    ushort* sh, const ushort* __restrict__ src, int src_stride, int t) {
  const int r = t >> 2;
  const int cb = (t & 3) * 32;
  const ushort* s = &src[(size_t)r * src_stride + cb];
  uint4 q0 = *(const uint4*)&s[0];
  uint4 q1 = *(const uint4*)&s[8];
  uint4 q2 = *(const uint4*)&s[16];
  uint4 q3 = *(const uint4*)&s[24];
  char* shb = (char*)sh + r * 256;
  const int c0 = cb * 2;
  *(uint4*)(shb + ((c0 +  0) ^ SWZ256(r))) = q0;
  *(uint4*)(shb + ((c0 + 16) ^ SWZ256(r))) = q1;
  *(uint4*)(shb + ((c0 + 32) ^ SWZ256(r))) = q2;
  *(uint4*)(shb + ((c0 + 48) ^ SWZ256(r))) = q3;
}

// ============================================================
// Per (b,c,h): cumsum(dA) scan + intra-chunk states via MFMA.
// Epilogue staged through LDS -> 4KB contiguous bursts.
// ============================================================
__global__ __launch_bounds__(256) void chunk_states_mfma(
    const ushort* __restrict__ xconv, const float* __restrict__ dt_bhl,
    const float* __restrict__ dA_bhl, float* __restrict__ dA_cs_g,
    float* __restrict__ Tg, ushort* __restrict__ states_bf) {
  const int blk = blockIdx.x;
  const int h = blk & (NH - 1);
  const int c = (blk / NH) & (NC - 1);
  const int b = blk / (NH * NC);
  const int t = threadIdx.x;
  const int lane = t & 63;
  const int wid = t >> 6;
  const int lr = lane & 15;
  const int lk = lane >> 4;
  __shared__ float cs[CHK];
  __shared__ ushort Xt2[64 * 64];   // [p][l] 128B pitch, SWZ64
  __shared__ ushort Bt2[128 * 64];  // [n][l] 128B pitch, SWZ64; reused as C-stage
  const size_t bh = (size_t)b * NH + h;
  const int rowbase = b * LQ + c * CHK;

  cs[t] = dA_bhl[bh * LQ + c * CHK + t];
  __syncthreads();
#pragma unroll
  for (int off = 1; off < CHK; off <<= 1) {
    const float add = (t >= off) ? cs[t - off] : 0.f;
    __syncthreads();
    cs[t] += add;
    __syncthreads();
  }
  const float total = cs[CHK - 1];
  dA_cs_g[(bh * NC + c) * CHK + t] = cs[t];
  if (t == 0) Tg[bh * NC + c] = total;

  f32x4 acc[4][2];
#pragma unroll
  for (int i = 0; i < 4; ++i)
#pragma unroll
    for (int j = 0; j < 2; ++j) acc[i][j] = (f32x4){0.f, 0.f, 0.f, 0.f};

  for (int lt = 0; lt < 4; ++lt) {
    const int l0 = lt * 64;
    __syncthreads();
    {  // stage Xt2: rows l -> [p][l], factor dt*exp(total-cs)
      const int sr = t >> 2;
      const int pb = (t & 3) * 16;
      const float f = dt_bhl[bh * LQ + c * CHK + l0 + sr] * expf(total - cs[l0 + sr]);
      const ushort* xs = &xconv[(size_t)(rowbase + l0 + sr) * CONVD + h * HD + pb];
      ushort xv[16];
      *(uint4*)&xv[0] = *(const uint4*)&xs[0];
      *(uint4*)&xv[8] = *(const uint4*)&xs[8];
      char* Xb = (char*)Xt2;
#pragma unroll
      for (int e = 0; e < 16; ++e) {
        const int p = pb + e;
        *(ushort*)(Xb + (p * 128 + ((sr * 2) ^ SWZ64(p)))) = f2bf(bf2f(xv[e]) * f);
      }
    }
    {  // stage Bt2: rows l -> [n][l]
      const int sr = t >> 2;
      const int nb = (t & 3) * 32;
      const ushort* bs = &xconv[(size_t)(rowbase + l0 + sr) * CONVD + DSSM + nb];
      ushort bv[32];
      *(uint4*)&bv[0]  = *(const uint4*)&bs[0];
      *(uint4*)&bv[8]  = *(const uint4*)&bs[8];
      *(uint4*)&bv[16] = *(const uint4*)&bs[16];
      *(uint4*)&bv[24] = *(const uint4*)&bs[24];
      char* Bb = (char*)Bt2;
#pragma unroll
      for (int e = 0; e < 32; ++e) {
        const int n = nb + e;
        *(ushort*)(Bb + (n * 128 + ((sr * 2) ^ SWZ64(n)))) = bv[e];
      }
    }
    __syncthreads();
#pragma unroll
    for (int ks = 0; ks < 2; ++ks) {
      const int kb = (ks * 32 + lk * 8) * 2;
      bf16x8 a4[4], b2[2];
#pragma unroll
      for (int i = 0; i < 4; ++i) {
        const int p = i * 16 + lr;
        a4[i] = *(const bf16x8*)((char*)Xt2 + (p * 128 + (kb ^ SWZ64(p))));
      }
#pragma unroll
      for (int j = 0; j < 2; ++j) {
        const int n = wid * 32 + j * 16 + lr;
        b2[j] = *(const bf16x8*)((char*)Bt2 + (n * 128 + (kb ^ SWZ64(n))));
      }
#pragma unroll
      for (int i = 0; i < 4; ++i)
#pragma unroll
        for (int j = 0; j < 2; ++j)
          acc[i][j] = __builtin_amdgcn_mfma_f32_16x16x32_bf16(a4[i], b2[j], acc[i][j], 0, 0, 0);
    }
  }
  // ---------- LDS-staged store: [p][n] linear (16 KB) ----------
  __syncthreads();
#pragma unroll
  for (int i = 0; i < 4; ++i)
#pragma unroll
    for (int j = 0; j < 2; ++j)
#pragma unroll
      for (int q = 0; q < 4; ++q)
        Bt2[(i * 16 + lk * 4 + q) * 128 + wid * 32 + j * 16 + lr] = f2bf(acc[i][j][q]);
  __syncthreads();
  const size_t sbase = ((size_t)((b * NC + c) * NH) + h) * (HD * DST);
#pragma unroll
  for (int it = 0; it < 4; ++it) {
    const int idx = it * 256 + t;  // 0..1023
    *(uint4*)&states_bf[sbase + (size_t)idx * 8] = *(const uint4*)&Bt2[idx * 8];
  }
}

// ============================================================
// Inter-chunk recurrence: reads states_bf, keeps P fp32, writes prev_bf.
// ============================================================
__global__ __launch_bounds__(256) void chunk_scan_kernel(
    const ushort* __restrict__ states_bf, ushort* __restrict__ prev_bf,
    const float* __restrict__ Tg) {
  const int blk = blockIdx.x;
  const int s = blk & 7;
  const int bh = blk >> 3;
  const int b = bh / NH;
  const int h = bh % NH;
  const int e = s * 1024 + threadIdx.x * 4;
  float4 P = make_float4(0.f, 0.f, 0.f, 0.f);
#pragma unroll
  for (int c = 0; c < NC; ++c) {
    const size_t idx = ((size_t)((b * NC + c) * NH) + h) * (HD * DST) + e;
    ushort4 s4 = *(const ushort4*)&states_bf[idx];
    ushort4 o;
    o.x = f2bf(P.x); o.y = f2bf(P.y); o.z = f2bf(P.z); o.w = f2bf(P.w);
    *(ushort4*)&prev_bf[idx] = o;
    const float ec = expf(Tg[(size_t)bh * NC + c]);
    P.x = fmaf(ec, P.x, bf2f(s4.x)); P.y = fmaf(ec, P.y, bf2f(s4.y));
    P.z = fmaf(ec, P.z, bf2f(s4.z)); P.w = fmaf(ec, P.w, bf2f(s4.w));
  }
}

// ============================================================
// Per (b,c,h): Y = (L ∘ C B^T) X + exp(cs)⊙(C prev^T) + D*x  via MFMA.
// y output in [H][M][64] layout; stored via LDS stage + 4 KB bursts.
// ============================================================
__global__ __launch_bounds__(256) void y_mfma_kernel(
    const ushort* __restrict__ xconv, const float* __restrict__ dt_bhl,
    const float* __restrict__ dA_cs_g, const ushort* __restrict__ prevb,
    const float* __restrict__ Dp, ushort* __restrict__ y2) {
  const int blk = blockIdx.x;
  const int h = blk & (NH - 1);
  const int c = (blk / NH) & (NC - 1);
  const int b = blk / (NH * NC);
  const int t = threadIdx.x;
  const int lane = t & 63;
  const int wid = t >> 6;
  const int wr = (wid >> 1) * 32;   // l-range base of this wave
  const int wc = (wid & 1) * 32;    // p/s-range base of this wave
  const int lr = lane & 15;
  const int lk = lane >> 4;
  __shared__ float cs[CHK];
  __shared__ ushort Ct[64 * 128];   // C tile, 256B pitch, SWZ256
  __shared__ ushort Bs[64 * 128];   // B tile, 256B pitch, SWZ256
  __shared__ ushort Gt[64 * 64];    // G tile (l x s) SWZ64; reused as Y-stage
  __shared__ ushort Xt[64 * 64];    // X^T tile (p x s), SWZ64
  const size_t bh = (size_t)b * NH + h;
  const size_t prevbase = ((size_t)((b * NC + c) * NH) + h) * (HD * DST);
  const int rowbase = b * LQ + c * CHK;
  cs[t] = dA_cs_g[(bh * NC + c) * CHK + t];
  const float Dh = Dp[h];
  __syncthreads();

  for (int lt = 0; lt < 4; ++lt) {
    const int l0 = lt * 64;
    __syncthreads();  // protect Ct/Gt/Xt from previous iteration readers
    stage_tile_128w(Ct, &xconv[(size_t)(rowbase + l0) * CONVD + DSSM + DST], CONVD, t);
    __syncthreads();
    bf16x8 af[2][4];
#pragma unroll
    for (int i = 0; i < 2; ++i)
#pragma unroll
      for (int ks = 0; ks < 4; ++ks) {
        const int row = wr + i * 16 + lr;
        af[i][ks] = *(const bf16x8*)((char*)Ct +
            (row * 256 + (((ks * 32 + lk * 8) * 2) ^ SWZ256(row))));
      }
    f32x4 acc[2][2];
#pragma unroll
    for (int i = 0; i < 2; ++i)
#pragma unroll
      for (int j = 0; j < 2; ++j) acc[i][j] = (f32x4){0.f, 0.f, 0.f, 0.f};
#pragma unroll
    for (int ks = 0; ks < 4; ++ks) {
      bf16x8 bp[2];
#pragma unroll
      for (int j = 0; j < 2; ++j) {
        const int p = wc + j * 16 + lr;
        bp[j] = *(const bf16x8*)&prevb[prevbase + (size_t)p * DST + ks * 32 + lk * 8];
      }
#pragma unroll
      for (int i = 0; i < 2; ++i)
#pragma unroll
        for (int j = 0; j < 2; ++j)
          acc[i][j] = __builtin_amdgcn_mfma_f32_16x16x32_bf16(af[i][ks], bp[j], acc[i][j], 0, 0, 0);
    }
#pragma unroll
    for (int i = 0; i < 2; ++i) {
#pragma unroll
      for (int q = 0; q < 4; ++q) {
        const float e = expf(cs[l0 + wr + i * 16 + lk * 4 + q]);
        acc[i][0][q] *= e;
        acc[i][1][q] *= e;
      }
    }

    for (int st = 0; st <= lt; ++st) {
      const int s0 = st * 64;
      __syncthreads();
      stage_tile_128w(Bs, &xconv[(size_t)(rowbase + s0) * CONVD + DSSM], CONVD, t);
      {  // stage Xt: rows s of x*dt -> [p][s]
        const int sr = t >> 2;
        const int pb = (t & 3) * 16;
        const float f = dt_bhl[bh * LQ + c * CHK + s0 + sr];
        const ushort* xs = &xconv[(size_t)(rowbase + s0 + sr) * CONVD + h * HD + pb];
        ushort xv[16];
        *(uint4*)&xv[0] = *(const uint4*)&xs[0];
        *(uint4*)&xv[8] = *(const uint4*)&xs[8];
        char* Xb = (char*)Xt;
#pragma unroll
        for (int e = 0; e < 16; ++e) {
          const int p = pb + e;
          *(ushort*)(Xb + (p * 128 + ((sr * 2) ^ SWZ64(p)))) = f2bf(bf2f(xv[e]) * f);
        }
      }
      __syncthreads();
      // G = C B^T
      f32x4 g2[2][2];
#pragma unroll
      for (int i = 0; i < 2; ++i)
#pragma unroll
        for (int j = 0; j < 2; ++j) g2[i][j] = (f32x4){0.f, 0.f, 0.f, 0.f};
#pragma unroll
      for (int ks = 0; ks < 4; ++ks) {
        bf16x8 bb[2];
#pragma unroll
        for (int j = 0; j < 2; ++j) {
          const int srow = wc + j * 16 + lr;
          bb[j] = *(const bf16x8*)((char*)Bs +
              (srow * 256 + (((ks * 32 + lk * 8) * 2) ^ SWZ256(srow))));
        }
#pragma unroll
        for (int i = 0; i < 2; ++i)
#pragma unroll
          for (int j = 0; j < 2; ++j)
            g2[i][j] = __builtin_amdgcn_mfma_f32_16x16x32_bf16(af[i][ks], bb[j], g2[i][j], 0, 0, 0);
      }
      // decay + causal mask, write G (bf16) to LDS
      {
        char* Gb = (char*)Gt;
#pragma unroll
        for (int i = 0; i < 2; ++i) {
#pragma unroll
          for (int q = 0; q < 4; ++q) {
            const int lloc = wr + i * 16 + lk * 4 + q;
            const int labs = l0 + lloc;
            const float cl = cs[labs];
#pragma unroll
            for (int j = 0; j < 2; ++j) {
              const int sloc = wc + j * 16 + lr;
              const int sabs = s0 + sloc;
              const float gv = (labs >= sabs) ? g2[i][j][q] * expf(cl - cs[sabs]) : 0.f;
              *(ushort*)(Gb + (lloc * 128 + ((sloc * 2) ^ SWZ64(lloc)))) = f2bf(gv);
            }
          }
        }
      }
      __syncthreads();
      // Y += G X
#pragma unroll
      for (int ks2 = 0; ks2 < 2; ++ks2) {
        const int kb = (ks2 * 32 + lk * 8) * 2;
        bf16x8 ga[2], xb[2];
#pragma unroll
        for (int i = 0; i < 2; ++i) {
          const int lloc = wr + i * 16 + lr;
          ga[i] = *(const bf16x8*)((char*)Gt + (lloc * 128 + (kb ^ SWZ64(lloc))));
        }
#pragma unroll
        for (int j = 0; j < 2; ++j) {
          const int p = wc + j * 16 + lr;
          xb[j] = *(const bf16x8*)((char*)Xt + (p * 128 + (kb ^ SWZ64(p))));
        }
#pragma unroll
        for (int i = 0; i < 2; ++i)
#pragma unroll
          for (int j = 0; j < 2; ++j)
            acc[i][j] = __builtin_amdgcn_mfma_f32_16x16x32_bf16(ga[i], xb[j], acc[i][j], 0, 0, 0);
      }
    }
    // ---------- epilogue: +D*x, stage 64x64 Y tile in Gt, linear copy ----------
    __syncthreads();  // all waves done reading Gt
#pragma unroll
    for (int i = 0; i < 2; ++i)
#pragma unroll
      for (int j = 0; j < 2; ++j)
#pragma unroll
        for (int q = 0; q < 4; ++q) {
          const int lloc = wr + i * 16 + lk * 4 + q;
          const int p = wc + j * 16 + lr;
          const float xv = bf2f(xconv[(size_t)(rowbase + l0 + lloc) * CONVD + h * HD + p]);
          Gt[lloc * 64 + p] = f2bf(acc[i][j][q] + Dh * xv);
        }
    __syncthreads();
    {
      const size_t ybase = ((size_t)h * MROWS + rowbase + l0) * HD;
#pragma unroll
      for (int it = 0; it < 2; ++it) {
        const int idx = it * 256 + t;  // 0..511
        *(uint4*)&y2[ybase + (size_t)idx * 8] = *(const uint4*)&Gt[idx * 8];
      }
    }
  }
}

// ============================================================
// yg = y*silu(z); rmsnorm; y read from [H][M][64] layout.
// ============================================================
__global__ __launch_bounds__(256) void gate_norm_kernel(
    const ushort* __restrict__ zx, const float* __restrict__ norm_w,
    const ushort* __restrict__ y2, ushort* __restrict__ ygbf) {
  const int m = blockIdx.x;
  const int t = threadIdx.x;
  __shared__ float red[4];
  float g[8];
  float ssum = 0.f;
#pragma unroll
  for (int j = 0; j < 2; ++j) {
    const int cb = t * 4 + j * 1024;
    const int hh = cb >> 6;
    const int pp = cb & 63;
    ushort4 yv = *(const ushort4*)&y2[((size_t)hh * MROWS + m) * HD + pp];
    ushort4 zv = *(const ushort4*)&zx[(size_t)m * DPROJ + cb];
    const float yy[4] = {bf2f(yv.x), bf2f(yv.y), bf2f(yv.z), bf2f(yv.w)};
    const float zz[4] = {bf2f(zv.x), bf2f(zv.y), bf2f(zv.z), bf2f(zv.w)};
#pragma unroll
    for (int q = 0; q < 4; ++q) {
      const float gv = yy[q] * silu_f(zz[q]);
      g[j * 4 + q] = gv;
      ssum = fmaf(gv, gv, ssum);
    }
  }
#pragma unroll
  for (int off = 32; off > 0; off >>= 1) ssum += __shfl_down(ssum, off, 64);
  if ((t & 63) == 0) red[t >> 6] = ssum;
  __syncthreads();
  const float tot = red[0] + red[1] + red[2] + red[3];
  const float sc = 1.0f / sqrtf(tot / (float)DSSM + 1e-5f);
#pragma unroll
  for (int j = 0; j < 2; ++j) {
    const int cb = t * 4 + j * 1024;
    float4 nw = *(const float4*)&norm_w[cb];
    ushort4 o;
    o.x = f2bf(g[j * 4 + 0] * sc * nw.x);
    o.y = f2bf(g[j * 4 + 1] * sc * nw.y);
    o.z = f2bf(g[j * 4 + 2] * sc * nw.z);
    o.w = f2bf(g[j * 4 + 3] * sc * nw.w);
    *(ushort4*)&ygbf[(size_t)m * DSSM + cb] = o;
  }
}

// ============================================================
extern "C" void kernel_launch(void* const* d_in, const int* in_sizes, int n_in,
                              void* d_out, int out_size, void* d_ws, size_t ws_size,
                              hipStream_t stream) {
  const float* u          = (const float*)d_in[0];
  const float* in_proj_w  = (const float*)d_in[1];
  const float* conv_w     = (const float*)d_in[2];
  const float* conv_b     = (const float*)d_in[3];
  const float* dt_bias    = (const float*)d_in[4];
  const float* A_log      = (const float*)d_in[5];
  const float* Dp         = (const float*)d_in[6];
  const float* norm_w     = (const float*)d_in[7];
  const float* out_proj_w = (const float*)d_in[8];
  float* out = (float*)d_out;

  float* ws = (float*)d_ws;
  float* zxR     = ws;
  float* xconvR  = zxR     + (size_t)MROWS * DPROJ;
  float* dt_bhl  = xconvR  + (size_t)MROWS * CONVD;
  float* dA_bhl  = dt_bhl  + (size_t)B_SZ * NH * LQ;
  float* dA_cs   = dA_bhl  + (size_t)B_SZ * NH * LQ;
  float* Tg      = dA_cs   + (size_t)B_SZ * NH * LQ;
  float* statesR = Tg      + (size_t)B_SZ * NH * NC;
  float* ybufR   = statesR + (size_t)B_SZ * NC * NH * HD * DST;

  // bf16 views (same regions, footprint unchanged):
  ushort* zx_bf    = (ushort*)zxR;                       // 4096 x 4384 bf16
  ushort* xconv_bf = (ushort*)xconvR;                    // 4096 x 2304 bf16
  ushort* ow_bf    = xconv_bf + (size_t)MROWS * CONVD;   // out_proj_w bf16 (disjoint half)
  ushort* states_bf = (ushort*)statesR;
  ushort* prev_bf   = states_bf + (size_t)B_SZ * NC * NH * HD * DST;
  ushort* u_bf  = (ushort*)ybufR;                        // dead after in-gemm
  ushort* w_bf  = u_bf + (size_t)MROWS * DMODEL;         // dead after in-gemm
  ushort* y2_bf = (ushort*)ybufR;                        // y_mfma output, [H][M][64]
  ushort* yg_bf = y2_bf + (size_t)MROWS * DSSM;          // gate_norm output [M][2048]

  const int n_u = MROWS * DMODEL;
  const int n_w = DPROJ * DMODEL;
  const int n_o = DMODEL * DSSM;

  // 1) casts for in_proj
  cast_f32_bf16_kernel<<<dim3(n_u / 1024), 256, 0, stream>>>(u, u_bf, n_u);
  cast_f32_bf16_kernel<<<dim3(n_w / 1024), 256, 0, stream>>>(in_proj_w, w_bf, n_w);
  // 2) zxbcdt = u @ in_proj_w^T  (bf16 out, global_load_lds pipeline)
  gemm_nt_bf16<true><<<dim3((DPROJ + 127) / 128, MROWS / 128), 256, 0, stream>>>(
      u_bf, w_bf, zx_bf, MROWS, DPROJ, DMODEL);
  // 3) fp32 dt / dA
  dt_kernel<<<dim3(MROWS), 256, 0, stream>>>(u, in_proj_w, dt_bias, A_log, dt_bhl, dA_bhl);
  // 4) causal dwconv + SiLU (bf16 in/out)
  conv_kernel<<<dim3(B_SZ * (LQ / 16)), 256, 0, stream>>>(zx_bf, conv_w, conv_b, xconv_bf);
  // 5) per-chunk cumsum + intra-chunk states (MFMA, LDS-staged stores)
  chunk_states_mfma<<<dim3(B_SZ * NC * NH), 256, 0, stream>>>(
      xconv_bf, dt_bhl, dA_bhl, dA_cs, Tg, states_bf);
  // 6) inter-chunk recurrence
  chunk_scan_kernel<<<dim3(B_SZ * NH * 8), 256, 0, stream>>>(states_bf, prev_bf, Tg);
  // 7) Y (MFMA, [H][M][64] layout, LDS-staged stores)
  y_mfma_kernel<<<dim3(B_SZ * NC * NH), 256, 0, stream>>>(
      xconv_bf, dt_bhl, dA_cs, prev_bf, Dp, y2_bf);
  // 8) cast out_proj_w
  cast_f32_bf16_kernel<<<dim3(n_o / 1024), 256, 0, stream>>>(out_proj_w, ow_bf, n_o);
  // 9) gate + RMSNorm -> bf16 [M][2048]
  gate_norm_kernel<<<dim3(MROWS), 256, 0, stream>>>(zx_bf, norm_w, y2_bf, yg_bf);
  // 10) out = yg @ out_proj_w^T (fp32 out, global_load_lds pipeline)
  gemm_nt_bf16<false><<<dim3(DMODEL / 128, MROWS / 128), 256, 0, stream>>>(
      yg_bf, ow_bf, out, MROWS, DMODEL, DSSM);
}

// Round 13
// 329.375 us; speedup vs baseline: 1.4781x; 1.0833x over previous
//
#include <hip/hip_runtime.h>
#include <cstdint>
#include <cstddef>

// ---------------- Mamba2 fwd: bf16-MFMA + global_load_lds GEMM pipeline ----------------
// B=2 L=2048 Dmodel=1024 Dssm=2048 H=32 P=64 N=128 chunk=256
#define B_SZ   2
#define LQ     2048
#define DMODEL 1024
#define DSSM   2048
#define NH     32
#define HD     64
#define DST    128
#define CONVD  2304
#define DPROJ  4384
#define NC     8
#define CHK    256
#define MROWS  (B_SZ*LQ)   // 4096

#define SWZ256(r) (((r) & 15) << 4)
#define SWZ64(r)  (((((r) & 7) ^ (((r) >> 3) & 7))) << 4)

__device__ __forceinline__ float silu_f(float x) { return x / (1.f + expf(-x)); }
__device__ __forceinline__ float softplus_f(float x) {
  return fmaxf(x, 0.f) + log1pf(expf(-fabsf(x)));
}
__device__ __forceinline__ ushort f2bf(float f) {  // RNE fp32->bf16
  uint32_t u = __float_as_uint(f);
  uint32_t r = (u + 0x7FFFu + ((u >> 16) & 1u)) >> 16;
  return (ushort)r;
}
__device__ __forceinline__ float bf2f(ushort u) {
  return __uint_as_float(((uint32_t)u) << 16);
}
// async global->LDS DMA, 16B per lane; LDS dest = wave-uniform base + lane*16
__device__ __forceinline__ void gload_lds16(const ushort* g, ushort* l) {
  __builtin_amdgcn_global_load_lds(
      (const __attribute__((address_space(1))) void*)g,
      (__attribute__((address_space(3))) void*)l, 16, 0, 0);
}

typedef __bf16 bf16x8 __attribute__((ext_vector_type(8)));
typedef float f32x4 __attribute__((ext_vector_type(4)));

// ============================================================
// cast fp32 -> bf16 (as ushort), 4 elems/thread
// ============================================================
__global__ __launch_bounds__(256) void cast_f32_bf16_kernel(
    const float* __restrict__ in, ushort* __restrict__ out, int n) {
  const int i = (blockIdx.x * 256 + threadIdx.x) * 4;
  if (i >= n) return;
  float4 v = *(const float4*)&in[i];
  ushort4 o;
  o.x = f2bf(v.x); o.y = f2bf(v.y); o.z = f2bf(v.z); o.w = f2bf(v.w);
  *(ushort4*)&out[i] = o;
}

// ============================================================
// bf16 MFMA GEMM (NT): C[m][n] = sum_k A[m][k]*B[n][k].
// Staging via global_load_lds (16B/lane DMA), linear LDS dest +
// PRE-SWIZZLED global source column. Epilogue: LDS-staged stores.
// (R12-verified: 137 -> <76 us per projection GEMM.)
// ============================================================
template<bool BF16OUT>
__global__ __launch_bounds__(256, 4) void gemm_nt_bf16(
    const ushort* __restrict__ A, const ushort* __restrict__ Bm,
    void* __restrict__ Cout, int M, int N, int K) {
  __shared__ ushort sh[128 * 128];   // 32 KB: As | Bs during K-loop, C-stage after
  ushort* As = sh;
  ushort* Bs = sh + 128 * 64;
  const int t = threadIdx.x;
  const int lane = t & 63;
  const int wid = t >> 6;
  const int wm = (wid >> 1) * 64;
  const int wn = (wid & 1) * 64;
  const int lr = lane & 15;
  const int lkb = (lane >> 4) * 8;   // k-elem offset for frag loads
  const int lk4 = (lane >> 4) * 4;   // n sub-offset in D
  // XCD swizzle (bijective: nwg % 8 == 0)
  const int gx = gridDim.x;
  int lin = blockIdx.y * gx + blockIdx.x;
  const int q8 = (gx * gridDim.y) >> 3;
  lin = (lin & 7) * q8 + (lin >> 3);
  const int m0 = (lin / gx) * 128;
  const int n0 = (lin % gx) * 128;

  // staging geometry: wave w covers rows {s2*32 + w*8 + ric}, ric = lane>>3,
  // 16B (8 ushorts) per lane. Pre-swizzle source col by ric<<3 (== (row&7)<<3).
  const int ric = lane >> 3;
  const int colsw = ((lane & 7) * 8) ^ (ric << 3);
  const size_t aoff0 = (size_t)(m0 + wid * 8 + ric) * K + colsw;
  size_t boff[4];
#pragma unroll
  for (int s2 = 0; s2 < 4; ++s2) {
    int gn = n0 + s2 * 32 + wid * 8 + ric;
    if (gn > N - 1) gn = N - 1;    // clamp tail rows (results masked at store)
    boff[s2] = (size_t)gn * K + colsw;
  }
  ushort* AsW = As + wid * 8 * 64;   // wave-uniform LDS base (s2=0)
  ushort* BsW = Bs + wid * 8 * 64;

  f32x4 acc[4][4];
#pragma unroll
  for (int i = 0; i < 4; ++i)
#pragma unroll
    for (int j = 0; j < 4; ++j) acc[i][j] = (f32x4){0.f, 0.f, 0.f, 0.f};

  const int NT = K >> 6;
  for (int kt = 0; kt < NT; ++kt) {
    const int k0 = kt << 6;
    __syncthreads();   // previous compute finished reading LDS
#pragma unroll
    for (int s2 = 0; s2 < 4; ++s2) {
      gload_lds16(&A[aoff0 + (size_t)s2 * 32 * K + k0], AsW + s2 * 32 * 64);
      gload_lds16(&Bm[boff[s2] + k0], BsW + s2 * 32 * 64);
    }
    __syncthreads();   // compiler drains vmcnt before barrier -> LDS ready
#pragma unroll
    for (int ks = 0; ks < 2; ++ks) {
      bf16x8 af[4], bfr[4];
#pragma unroll
      for (int i = 0; i < 4; ++i) {
        const int ra = wm + i * 16 + lr;
        const int ea = (ra * 64 + ks * 32 + lkb) ^ ((ra & 7) << 3);
        af[i] = *(const bf16x8*)&As[ea];
        const int rb = wn + i * 16 + lr;
        const int eb = (rb * 64 + ks * 32 + lkb) ^ ((rb & 7) << 3);
        bfr[i] = *(const bf16x8*)&Bs[eb];
      }
      // swapped operands: lane's 4 D-elems = 4 consecutive n at fixed m
#pragma unroll
      for (int i = 0; i < 4; ++i)
#pragma unroll
        for (int j = 0; j < 4; ++j)
          acc[i][j] = __builtin_amdgcn_mfma_f32_16x16x32_bf16(bfr[j], af[i], acc[i][j], 0, 0, 0);
    }
  }
  // ---------- LDS-staged epilogue ----------
  __syncthreads();  // all frag reads of As/Bs done
  if constexpr (BF16OUT) {
#pragma unroll
    for (int i = 0; i < 4; ++i) {
      const int ml = wm + i * 16 + lr;
#pragma unroll
      for (int j = 0; j < 4; ++j) {
        ushort4 o;
        o.x = f2bf(acc[i][j][0]); o.y = f2bf(acc[i][j][1]);
        o.z = f2bf(acc[i][j][2]); o.w = f2bf(acc[i][j][3]);
        *(ushort4*)&sh[ml * 128 + wn + j * 16 + lk4] = o;
      }
    }
    __syncthreads();
    ushort* Cg = (ushort*)Cout;
#pragma unroll
    for (int it = 0; it < 8; ++it) {
      const int idx = it * 256 + t;          // 0..2047
      const int r = idx >> 4;                // 0..127
      const int cc = (idx & 15) * 8;         // col (ushort)
      const int gn = n0 + cc;
      if (gn < N)
        *(uint4*)&Cg[(size_t)(m0 + r) * N + gn] = *(const uint4*)&sh[r * 128 + cc];
    }
  } else {
    // fp32: two half-tile passes (64 rows x 128 cols = 32 KB each)
    float* Cf = (float*)sh;
    float* Cg = (float*)Cout;
#pragma unroll
    for (int p = 0; p < 2; ++p) {
      __syncthreads();
#pragma unroll
      for (int i2 = 0; i2 < 2; ++i2) {
        const int i = p * 2 + i2;
        const int cr = (wid >> 1) * 32 + i2 * 16 + lr;   // compressed row 0..63
#pragma unroll
        for (int j = 0; j < 4; ++j)
          *(float4*)&Cf[cr * 128 + wn + j * 16 + lk4] =
              make_float4(acc[i][j][0], acc[i][j][1], acc[i][j][2], acc[i][j][3]);
      }
      __syncthreads();
#pragma unroll
      for (int it = 0; it < 8; ++it) {
        const int idx = it * 256 + t;        // 0..2047
        const int cr = idx >> 5;             // 0..63
        const int cc = (idx & 31) * 4;
        const int gm = m0 + (cr >> 5) * 64 + p * 32 + (cr & 31);
        const int gn = n0 + cc;
        if (gn < N)
          *(float4*)&Cg[(size_t)gm * N + gn] = *(const float4*)&Cf[cr * 128 + cc];
      }
    }
  }
}

// ============================================================
// fp32 dt (R13 rewrite): 16-row tiled. u rows staged in LDS (pad 1032),
// lane (h=t>>3, p=t&7) reads float4 at k=p*4+32*kk -> 8 p-lanes cover
// 32 consecutive floats = all 32 banks (conflict-free, h-broadcast).
// Each w float4 loaded once, reused across 16 rows (w traffic /16).
// ============================================================
#define DTROWS 16
__global__ __launch_bounds__(256, 2) void dt_kernel(
    const float* __restrict__ u, const float* __restrict__ w,
    const float* __restrict__ dt_bias, const float* __restrict__ A_log,
    float* __restrict__ dt_bhl, float* __restrict__ dA_bhl) {
  __shared__ float us[DTROWS][1032];   // 64.5 KB, +8 pad
  const int t = threadIdx.x;
  const int m0 = blockIdx.x * DTROWS;
  {  // coalesced load: 16 lanes/row, lane covers cols c0 + 64*q
    const int lrw = t >> 4;
    const int c0 = (t & 15) * 4;
    const float* src = &u[(size_t)(m0 + lrw) * DMODEL];
#pragma unroll
    for (int q = 0; q < 16; ++q)
      *(float4*)&us[lrw][c0 + q * 64] = *(const float4*)&src[c0 + q * 64];
  }
  __syncthreads();
  const int h = t >> 3;
  const int p = t & 7;
  const float* wr = &w[(size_t)(DSSM + CONVD + h) * DMODEL];
  float s[DTROWS];
#pragma unroll
  for (int r = 0; r < DTROWS; ++r) s[r] = 0.f;
  for (int kk = 0; kk < 32; ++kk) {
    const int k4 = p * 4 + kk * 32;
    const float4 wv = *(const float4*)&wr[k4];
#pragma unroll
    for (int r = 0; r < DTROWS; ++r) {
      const float4 uv = *(const float4*)&us[r][k4];
      s[r] = fmaf(wv.x, uv.x, s[r]);
      s[r] = fmaf(wv.y, uv.y, s[r]);
      s[r] = fmaf(wv.z, uv.z, s[r]);
      s[r] = fmaf(wv.w, uv.w, s[r]);
    }
  }
#pragma unroll
  for (int r = 0; r < DTROWS; ++r) {
    s[r] += __shfl_down(s[r], 4, 8);
    s[r] += __shfl_down(s[r], 2, 8);
    s[r] += __shfl_down(s[r], 1, 8);
  }
  if (p == 0) {
    const float nA = -expf(A_log[h]);
    const float db = dt_bias[h];
#pragma unroll
    for (int r = 0; r < DTROWS; ++r) {
      const int m = m0 + r;
      const int b = m >> 11;
      const int l = m & 2047;
      const float dtv = softplus_f(s[r] + db);
      const size_t o = ((size_t)b * NH + h) * LQ + l;
      dt_bhl[o] = dtv;
      dA_bhl[o] = nA * dtv;
    }
  }
}

// ============================================================
// Depthwise causal conv(K=4)+bias+SiLU over xBC. bf16 in/out, fp32 math.
// ============================================================
__global__ __launch_bounds__(256) void conv_kernel(
    const ushort* __restrict__ zx, const float* __restrict__ conv_w,
    const float* __restrict__ conv_b, ushort* __restrict__ xconv) {
  const int ROWS = 16;
  const int nrb = LQ / ROWS;
  const int blk = blockIdx.x;
  const int b = blk / nrb;
  const int r0 = (blk % nrb) * ROWS;
  const int t = threadIdx.x;

  float w0[9], w1[9], w2[9], w3[9], bsv[9], h0[9], h1[9], h2[9];
#pragma unroll
  for (int j = 0; j < 9; ++j) {
    const int cch = t + 256 * j;
    w0[j] = conv_w[cch * 4 + 0]; w1[j] = conv_w[cch * 4 + 1];
    w2[j] = conv_w[cch * 4 + 2]; w3[j] = conv_w[cch * 4 + 3];
    bsv[j] = conv_b[cch];
    h0[j] = (r0 - 3 >= 0) ? bf2f(zx[(size_t)(b * LQ + r0 - 3) * DPROJ + DSSM + cch]) : 0.f;
    h1[j] = (r0 - 2 >= 0) ? bf2f(zx[(size_t)(b * LQ + r0 - 2) * DPROJ + DSSM + cch]) : 0.f;
    h2[j] = (r0 - 1 >= 0) ? bf2f(zx[(size_t)(b * LQ + r0 - 1) * DPROJ + DSSM + cch]) : 0.f;
  }
  for (int r = 0; r < ROWS; ++r) {
    const size_t ibase = (size_t)(b * LQ + r0 + r) * DPROJ + DSSM;
    const size_t obase = (size_t)(b * LQ + r0 + r) * CONVD;
#pragma unroll
    for (int j = 0; j < 9; ++j) {
      const int cch = t + 256 * j;
      const float cur = bf2f(zx[ibase + cch]);
      float a = bsv[j] + w0[j] * h0[j] + w1[j] * h1[j] + w2[j] * h2[j] + w3[j] * cur;
      xconv[obase + cch] = f2bf(silu_f(a));
      h0[j] = h1[j]; h1[j] = h2[j]; h2[j] = cur;
    }
  }
}

// ============================================================
// Stage a [64 rows][128 cols] bf16 tile -> LDS, 256B pitch, SWZ256.
// ============================================================
__device__ __forceinline__ void stage_tile_128w(
    ushort* sh, const ushort* __restrict__ src, int src_stride, int t) {
  const int r = t >> 2;
  const int cb = (t & 3) * 32;
  const ushort* s = &src[(size_t)r * src_stride + cb];
  uint4 q0 = *(const uint4*)&s[0];
  uint4 q1 = *(const uint4*)&s[8];
  uint4 q2 = *(const uint4*)&s[16];
  uint4 q3 = *(const uint4*)&s[24];
  char* shb = (char*)sh + r * 256;
  const int c0 = cb * 2;
  *(uint4*)(shb + ((c0 +  0) ^ SWZ256(r))) = q0;
  *(uint4*)(shb + ((c0 + 16) ^ SWZ256(r))) = q1;
  *(uint4*)(shb + ((c0 + 32) ^ SWZ256(r))) = q2;
  *(uint4*)(shb + ((c0 + 48) ^ SWZ256(r))) = q3;
}

// ============================================================
// Per (b,c,h): cumsum(dA) scan + intra-chunk states via MFMA.
// Epilogue staged through LDS -> 4KB contiguous bursts.
// ============================================================
__global__ __launch_bounds__(256) void chunk_states_mfma(
    const ushort* __restrict__ xconv, const float* __restrict__ dt_bhl,
    const float* __restrict__ dA_bhl, float* __restrict__ dA_cs_g,
    float* __restrict__ Tg, ushort* __restrict__ states_bf) {
  const int blk = blockIdx.x;
  const int h = blk & (NH - 1);
  const int c = (blk / NH) & (NC - 1);
  const int b = blk / (NH * NC);
  const int t = threadIdx.x;
  const int lane = t & 63;
  const int wid = t >> 6;
  const int lr = lane & 15;
  const int lk = lane >> 4;
  __shared__ float cs[CHK];
  __shared__ ushort Xt2[64 * 64];   // [p][l] 128B pitch, SWZ64
  __shared__ ushort Bt2[128 * 64];  // [n][l] 128B pitch, SWZ64; reused as C-stage
  const size_t bh = (size_t)b * NH + h;
  const int rowbase = b * LQ + c * CHK;

  cs[t] = dA_bhl[bh * LQ + c * CHK + t];
  __syncthreads();
#pragma unroll
  for (int off = 1; off < CHK; off <<= 1) {
    const float add = (t >= off) ? cs[t - off] : 0.f;
    __syncthreads();
    cs[t] += add;
    __syncthreads();
  }
  const float total = cs[CHK - 1];
  dA_cs_g[(bh * NC + c) * CHK + t] = cs[t];
  if (t == 0) Tg[bh * NC + c] = total;

  f32x4 acc[4][2];
#pragma unroll
  for (int i = 0; i < 4; ++i)
#pragma unroll
    for (int j = 0; j < 2; ++j) acc[i][j] = (f32x4){0.f, 0.f, 0.f, 0.f};

  for (int lt = 0; lt < 4; ++lt) {
    const int l0 = lt * 64;
    __syncthreads();
    {  // stage Xt2: rows l -> [p][l], factor dt*exp(total-cs)
      const int sr = t >> 2;
      const int pb = (t & 3) * 16;
      const float f = dt_bhl[bh * LQ + c * CHK + l0 + sr] * expf(total - cs[l0 + sr]);
      const ushort* xs = &xconv[(size_t)(rowbase + l0 + sr) * CONVD + h * HD + pb];
      ushort xv[16];
      *(uint4*)&xv[0] = *(const uint4*)&xs[0];
      *(uint4*)&xv[8] = *(const uint4*)&xs[8];
      char* Xb = (char*)Xt2;
#pragma unroll
      for (int e = 0; e < 16; ++e) {
        const int p = pb + e;
        *(ushort*)(Xb + (p * 128 + ((sr * 2) ^ SWZ64(p)))) = f2bf(bf2f(xv[e]) * f);
      }
    }
    {  // stage Bt2: rows l -> [n][l]
      const int sr = t >> 2;
      const int nb = (t & 3) * 32;
      const ushort* bs = &xconv[(size_t)(rowbase + l0 + sr) * CONVD + DSSM + nb];
      ushort bv[32];
      *(uint4*)&bv[0]  = *(const uint4*)&bs[0];
      *(uint4*)&bv[8]  = *(const uint4*)&bs[8];
      *(uint4*)&bv[16] = *(const uint4*)&bs[16];
      *(uint4*)&bv[24] = *(const uint4*)&bs[24];
      char* Bb = (char*)Bt2;
#pragma unroll
      for (int e = 0; e < 32; ++e) {
        const int n = nb + e;
        *(ushort*)(Bb + (n * 128 + ((sr * 2) ^ SWZ64(n)))) = bv[e];
      }
    }
    __syncthreads();
#pragma unroll
    for (int ks = 0; ks < 2; ++ks) {
      const int kb = (ks * 32 + lk * 8) * 2;
      bf16x8 a4[4], b2[2];
#pragma unroll
      for (int i = 0; i < 4; ++i) {
        const int p = i * 16 + lr;
        a4[i] = *(const bf16x8*)((char*)Xt2 + (p * 128 + (kb ^ SWZ64(p))));
      }
#pragma unroll
      for (int j = 0; j < 2; ++j) {
        const int n = wid * 32 + j * 16 + lr;
        b2[j] = *(const bf16x8*)((char*)Bt2 + (n * 128 + (kb ^ SWZ64(n))));
      }
#pragma unroll
      for (int i = 0; i < 4; ++i)
#pragma unroll
        for (int j = 0; j < 2; ++j)
          acc[i][j] = __builtin_amdgcn_mfma_f32_16x16x32_bf16(a4[i], b2[j], acc[i][j], 0, 0, 0);
    }
  }
  // ---------- LDS-staged store: [p][n] linear (16 KB) ----------
  __syncthreads();
#pragma unroll
  for (int i = 0; i < 4; ++i)
#pragma unroll
    for (int j = 0; j < 2; ++j)
#pragma unroll
      for (int q = 0; q < 4; ++q)
        Bt2[(i * 16 + lk * 4 + q) * 128 + wid * 32 + j * 16 + lr] = f2bf(acc[i][j][q]);
  __syncthreads();
  const size_t sbase = ((size_t)((b * NC + c) * NH) + h) * (HD * DST);
#pragma unroll
  for (int it = 0; it < 4; ++it) {
    const int idx = it * 256 + t;  // 0..1023
    *(uint4*)&states_bf[sbase + (size_t)idx * 8] = *(const uint4*)&Bt2[idx * 8];
  }
}

// ============================================================
// Inter-chunk recurrence: reads states_bf, keeps P fp32, writes prev_bf.
// ============================================================
__global__ __launch_bounds__(256) void chunk_scan_kernel(
    const ushort* __restrict__ states_bf, ushort* __restrict__ prev_bf,
    const float* __restrict__ Tg) {
  const int blk = blockIdx.x;
  const int s = blk & 7;
  const int bh = blk >> 3;
  const int b = bh / NH;
  const int h = bh % NH;
  const int e = s * 1024 + threadIdx.x * 4;
  float4 P = make_float4(0.f, 0.f, 0.f, 0.f);
#pragma unroll
  for (int c = 0; c < NC; ++c) {
    const size_t idx = ((size_t)((b * NC + c) * NH) + h) * (HD * DST) + e;
    ushort4 s4 = *(const ushort4*)&states_bf[idx];
    ushort4 o;
    o.x = f2bf(P.x); o.y = f2bf(P.y); o.z = f2bf(P.z); o.w = f2bf(P.w);
    *(ushort4*)&prev_bf[idx] = o;
    const float ec = expf(Tg[(size_t)bh * NC + c]);
    P.x = fmaf(ec, P.x, bf2f(s4.x)); P.y = fmaf(ec, P.y, bf2f(s4.y));
    P.z = fmaf(ec, P.z, bf2f(s4.z)); P.w = fmaf(ec, P.w, bf2f(s4.w));
  }
}

// ============================================================
// Per (b,c,h): Y = (L ∘ C B^T) X + exp(cs)⊙(C prev^T) + D*x  via MFMA.
// y output in [H][M][64] layout; stored via LDS stage + 4 KB bursts.
// ============================================================
__global__ __launch_bounds__(256) void y_mfma_kernel(
    const ushort* __restrict__ xconv, const float* __restrict__ dt_bhl,
    const float* __restrict__ dA_cs_g, const ushort* __restrict__ prevb,
    const float* __restrict__ Dp, ushort* __restrict__ y2) {
  const int blk = blockIdx.x;
  const int h = blk & (NH - 1);
  const int c = (blk / NH) & (NC - 1);
  const int b = blk / (NH * NC);
  const int t = threadIdx.x;
  const int lane = t & 63;
  const int wid = t >> 6;
  const int wr = (wid >> 1) * 32;   // l-range base of this wave
  const int wc = (wid & 1) * 32;    // p/s-range base of this wave
  const int lr = lane & 15;
  const int lk = lane >> 4;
  __shared__ float cs[CHK];
  __shared__ ushort Ct[64 * 128];   // C tile, 256B pitch, SWZ256
  __shared__ ushort Bs[64 * 128];   // B tile, 256B pitch, SWZ256
  __shared__ ushort Gt[64 * 64];    // G tile (l x s) SWZ64; reused as Y-stage
  __shared__ ushort Xt[64 * 64];    // X^T tile (p x s), SWZ64
  const size_t bh = (size_t)b * NH + h;
  const size_t prevbase = ((size_t)((b * NC + c) * NH) + h) * (HD * DST);
  const int rowbase = b * LQ + c * CHK;
  cs[t] = dA_cs_g[(bh * NC + c) * CHK + t];
  const float Dh = Dp[h];
  __syncthreads();

  for (int lt = 0; lt < 4; ++lt) {
    const int l0 = lt * 64;
    __syncthreads();  // protect Ct/Gt/Xt from previous iteration readers
    stage_tile_128w(Ct, &xconv[(size_t)(rowbase + l0) * CONVD + DSSM + DST], CONVD, t);
    __syncthreads();
    bf16x8 af[2][4];
#pragma unroll
    for (int i = 0; i < 2; ++i)
#pragma unroll
      for (int ks = 0; ks < 4; ++ks) {
        const int row = wr + i * 16 + lr;
        af[i][ks] = *(const bf16x8*)((char*)Ct +
            (row * 256 + (((ks * 32 + lk * 8) * 2) ^ SWZ256(row))));
      }
    f32x4 acc[2][2];
#pragma unroll
    for (int i = 0; i < 2; ++i)
#pragma unroll
      for (int j = 0; j < 2; ++j) acc[i][j] = (f32x4){0.f, 0.f, 0.f, 0.f};
#pragma unroll
    for (int ks = 0; ks < 4; ++ks) {
      bf16x8 bp[2];
#pragma unroll
      for (int j = 0; j < 2; ++j) {
        const int p = wc + j * 16 + lr;
        bp[j] = *(const bf16x8*)&prevb[prevbase + (size_t)p * DST + ks * 32 + lk * 8];
      }
#pragma unroll
      for (int i = 0; i < 2; ++i)
#pragma unroll
        for (int j = 0; j < 2; ++j)
          acc[i][j] = __builtin_amdgcn_mfma_f32_16x16x32_bf16(af[i][ks], bp[j], acc[i][j], 0, 0, 0);
    }
#pragma unroll
    for (int i = 0; i < 2; ++i) {
#pragma unroll
      for (int q = 0; q < 4; ++q) {
        const float e = expf(cs[l0 + wr + i * 16 + lk * 4 + q]);
        acc[i][0][q] *= e;
        acc[i][1][q] *= e;
      }
    }

    for (int st = 0; st <= lt; ++st) {
      const int s0 = st * 64;
      __syncthreads();
      stage_tile_128w(Bs, &xconv[(size_t)(rowbase + s0) * CONVD + DSSM], CONVD, t);
      {  // stage Xt: rows s of x*dt -> [p][s]
        const int sr = t >> 2;
        const int pb = (t & 3) * 16;
        const float f = dt_bhl[bh * LQ + c * CHK + s0 + sr];
        const ushort* xs = &xconv[(size_t)(rowbase + s0 + sr) * CONVD + h * HD + pb];
        ushort xv[16];
        *(uint4*)&xv[0] = *(const uint4*)&xs[0];
        *(uint4*)&xv[8] = *(const uint4*)&xs[8];
        char* Xb = (char*)Xt;
#pragma unroll
        for (int e = 0; e < 16; ++e) {
          const int p = pb + e;
          *(ushort*)(Xb + (p * 128 + ((sr * 2) ^ SWZ64(p)))) = f2bf(bf2f(xv[e]) * f);
        }
      }
      __syncthreads();
      // G = C B^T
      f32x4 g2[2][2];
#pragma unroll
      for (int i = 0; i < 2; ++i)
#pragma unroll
        for (int j = 0; j < 2; ++j) g2[i][j] = (f32x4){0.f, 0.f, 0.f, 0.f};
#pragma unroll
      for (int ks = 0; ks < 4; ++ks) {
        bf16x8 bb[2];
#pragma unroll
        for (int j = 0; j < 2; ++j) {
          const int srow = wc + j * 16 + lr;
          bb[j] = *(const bf16x8*)((char*)Bs +
              (srow * 256 + (((ks * 32 + lk * 8) * 2) ^ SWZ256(srow))));
        }
#pragma unroll
        for (int i = 0; i < 2; ++i)
#pragma unroll
          for (int j = 0; j < 2; ++j)
            g2[i][j] = __builtin_amdgcn_mfma_f32_16x16x32_bf16(af[i][ks], bb[j], g2[i][j], 0, 0, 0);
      }
      // decay + causal mask, write G (bf16) to LDS
      {
        char* Gb = (char*)Gt;
#pragma unroll
        for (int i = 0; i < 2; ++i) {
#pragma unroll
          for (int q = 0; q < 4; ++q) {
            const int lloc = wr + i * 16 + lk * 4 + q;
            const int labs = l0 + lloc;
            const float cl = cs[labs];
#pragma unroll
            for (int j = 0; j < 2; ++j) {
              const int sloc = wc + j * 16 + lr;
              const int sabs = s0 + sloc;
              const float gv = (labs >= sabs) ? g2[i][j][q] * expf(cl - cs[sabs]) : 0.f;
              *(ushort*)(Gb + (lloc * 128 + ((sloc * 2) ^ SWZ64(lloc)))) = f2bf(gv);
            }
          }
        }
      }
      __syncthreads();
      // Y += G X
#pragma unroll
      for (int ks2 = 0; ks2 < 2; ++ks2) {
        const int kb = (ks2 * 32 + lk * 8) * 2;
        bf16x8 ga[2], xb[2];
#pragma unroll
        for (int i = 0; i < 2; ++i) {
          const int lloc = wr + i * 16 + lr;
          ga[i] = *(const bf16x8*)((char*)Gt + (lloc * 128 + (kb ^ SWZ64(lloc))));
        }
#pragma unroll
        for (int j = 0; j < 2; ++j) {
          const int p = wc + j * 16 + lr;
          xb[j] = *(const bf16x8*)((char*)Xt + (p * 128 + (kb ^ SWZ64(p))));
        }
#pragma unroll
        for (int i = 0; i < 2; ++i)
#pragma unroll
          for (int j = 0; j < 2; ++j)
            acc[i][j] = __builtin_amdgcn_mfma_f32_16x16x32_bf16(ga[i], xb[j], acc[i][j], 0, 0, 0);
      }
    }
    // ---------- epilogue: +D*x, stage 64x64 Y tile in Gt, linear copy ----------
    __syncthreads();  // all waves done reading Gt
#pragma unroll
    for (int i = 0; i < 2; ++i)
#pragma unroll
      for (int j = 0; j < 2; ++j)
#pragma unroll
        for (int q = 0; q < 4; ++q) {
          const int lloc = wr + i * 16 + lk * 4 + q;
          const int p = wc + j * 16 + lr;
          const float xv = bf2f(xconv[(size_t)(rowbase + l0 + lloc) * CONVD + h * HD + p]);
          Gt[lloc * 64 + p] = f2bf(acc[i][j][q] + Dh * xv);
        }
    __syncthreads();
    {
      const size_t ybase = ((size_t)h * MROWS + rowbase + l0) * HD;
#pragma unroll
      for (int it = 0; it < 2; ++it) {
        const int idx = it * 256 + t;  // 0..511
        *(uint4*)&y2[ybase + (size_t)idx * 8] = *(const uint4*)&Gt[idx * 8];
      }
    }
  }
}

// ============================================================
// yg = y*silu(z); rmsnorm; y read from [H][M][64] layout.
// ============================================================
__global__ __launch_bounds__(256) void gate_norm_kernel(
    const ushort* __restrict__ zx, const float* __restrict__ norm_w,
    const ushort* __restrict__ y2, ushort* __restrict__ ygbf) {
  const int m = blockIdx.x;
  const int t = threadIdx.x;
  __shared__ float red[4];
  float g[8];
  float ssum = 0.f;
#pragma unroll
  for (int j = 0; j < 2; ++j) {
    const int cb = t * 4 + j * 1024;
    const int hh = cb >> 6;
    const int pp = cb & 63;
    ushort4 yv = *(const ushort4*)&y2[((size_t)hh * MROWS + m) * HD + pp];
    ushort4 zv = *(const ushort4*)&zx[(size_t)m * DPROJ + cb];
    const float yy[4] = {bf2f(yv.x), bf2f(yv.y), bf2f(yv.z), bf2f(yv.w)};
    const float zz[4] = {bf2f(zv.x), bf2f(zv.y), bf2f(zv.z), bf2f(zv.w)};
#pragma unroll
    for (int q = 0; q < 4; ++q) {
      const float gv = yy[q] * silu_f(zz[q]);
      g[j * 4 + q] = gv;
      ssum = fmaf(gv, gv, ssum);
    }
  }
#pragma unroll
  for (int off = 32; off > 0; off >>= 1) ssum += __shfl_down(ssum, off, 64);
  if ((t & 63) == 0) red[t >> 6] = ssum;
  __syncthreads();
  const float tot = red[0] + red[1] + red[2] + red[3];
  const float sc = 1.0f / sqrtf(tot / (float)DSSM + 1e-5f);
#pragma unroll
  for (int j = 0; j < 2; ++j) {
    const int cb = t * 4 + j * 1024;
    float4 nw = *(const float4*)&norm_w[cb];
    ushort4 o;
    o.x = f2bf(g[j * 4 + 0] * sc * nw.x);
    o.y = f2bf(g[j * 4 + 1] * sc * nw.y);
    o.z = f2bf(g[j * 4 + 2] * sc * nw.z);
    o.w = f2bf(g[j * 4 + 3] * sc * nw.w);
    *(ushort4*)&ygbf[(size_t)m * DSSM + cb] = o;
  }
}

// ============================================================
extern "C" void kernel_launch(void* const* d_in, const int* in_sizes, int n_in,
                              void* d_out, int out_size, void* d_ws, size_t ws_size,
                              hipStream_t stream) {
  const float* u          = (const float*)d_in[0];
  const float* in_proj_w  = (const float*)d_in[1];
  const float* conv_w     = (const float*)d_in[2];
  const float* conv_b     = (const float*)d_in[3];
  const float* dt_bias    = (const float*)d_in[4];
  const float* A_log      = (const float*)d_in[5];
  const float* Dp         = (const float*)d_in[6];
  const float* norm_w     = (const float*)d_in[7];
  const float* out_proj_w = (const float*)d_in[8];
  float* out = (float*)d_out;

  float* ws = (float*)d_ws;
  float* zxR     = ws;
  float* xconvR  = zxR     + (size_t)MROWS * DPROJ;
  float* dt_bhl  = xconvR  + (size_t)MROWS * CONVD;
  float* dA_bhl  = dt_bhl  + (size_t)B_SZ * NH * LQ;
  float* dA_cs   = dA_bhl  + (size_t)B_SZ * NH * LQ;
  float* Tg      = dA_cs   + (size_t)B_SZ * NH * LQ;
  float* statesR = Tg      + (size_t)B_SZ * NH * NC;
  float* ybufR   = statesR + (size_t)B_SZ * NC * NH * HD * DST;

  // bf16 views (same regions, footprint unchanged):
  ushort* zx_bf    = (ushort*)zxR;                       // 4096 x 4384 bf16
  ushort* xconv_bf = (ushort*)xconvR;                    // 4096 x 2304 bf16
  ushort* ow_bf    = xconv_bf + (size_t)MROWS * CONVD;   // out_proj_w bf16 (disjoint half)
  ushort* states_bf = (ushort*)statesR;
  ushort* prev_bf   = states_bf + (size_t)B_SZ * NC * NH * HD * DST;
  ushort* u_bf  = (ushort*)ybufR;                        // dead after in-gemm
  ushort* w_bf  = u_bf + (size_t)MROWS * DMODEL;         // dead after in-gemm
  ushort* y2_bf = (ushort*)ybufR;                        // y_mfma output, [H][M][64]
  ushort* yg_bf = y2_bf + (size_t)MROWS * DSSM;          // gate_norm output [M][2048]

  const int n_u = MROWS * DMODEL;
  const int n_w = DPROJ * DMODEL;
  const int n_o = DMODEL * DSSM;

  // 1) casts for in_proj
  cast_f32_bf16_kernel<<<dim3(n_u / 1024), 256, 0, stream>>>(u, u_bf, n_u);
  cast_f32_bf16_kernel<<<dim3(n_w / 1024), 256, 0, stream>>>(in_proj_w, w_bf, n_w);
  // 2) zxbcdt = u @ in_proj_w^T  (bf16 out, global_load_lds pipeline)
  gemm_nt_bf16<true><<<dim3((DPROJ + 127) / 128, MROWS / 128), 256, 0, stream>>>(
      u_bf, w_bf, zx_bf, MROWS, DPROJ, DMODEL);
  // 3) fp32 dt / dA (16-row tiled, conflict-free)
  dt_kernel<<<dim3(MROWS / DTROWS), 256, 0, stream>>>(
      u, in_proj_w, dt_bias, A_log, dt_bhl, dA_bhl);
  // 4) causal dwconv + SiLU (bf16 in/out)
  conv_kernel<<<dim3(B_SZ * (LQ / 16)), 256, 0, stream>>>(zx_bf, conv_w, conv_b, xconv_bf);
  // 5) per-chunk cumsum + intra-chunk states (MFMA, LDS-staged stores)
  chunk_states_mfma<<<dim3(B_SZ * NC * NH), 256, 0, stream>>>(
      xconv_bf, dt_bhl, dA_bhl, dA_cs, Tg, states_bf);
  // 6) inter-chunk recurrence
  chunk_scan_kernel<<<dim3(B_SZ * NH * 8), 256, 0, stream>>>(states_bf, prev_bf, Tg);
  // 7) Y (MFMA, [H][M][64] layout, LDS-staged stores)
  y_mfma_kernel<<<dim3(B_SZ * NC * NH), 256, 0, stream>>>(
      xconv_bf, dt_bhl, dA_cs, prev_bf, Dp, y2_bf);
  // 8) cast out_proj_w
  cast_f32_bf16_kernel<<<dim3(n_o / 1024), 256, 0, stream>>>(out_proj_w, ow_bf, n_o);
  // 9) gate + RMSNorm -> bf16 [M][2048]
  gate_norm_kernel<<<dim3(MROWS), 256, 0, stream>>>(zx_bf, norm_w, y2_bf, yg_bf);
  // 10) out = yg @ out_proj_w^T (fp32 out, global_load_lds pipeline)
  gemm_nt_bf16<false><<<dim3(DMODEL / 128, MROWS / 128), 256, 0, stream>>>(
      yg_bf, ow_bf, out, MROWS, DMODEL, DSSM);
}